// Round 15
// baseline (4199.821 us; speedup 1.0000x reference)
//
#include <hip/hip_runtime.h>

#define B_   64
#define T_   256
#define H_   512
#define F0_  256
#define C_   32
#define NBUF 32

typedef short short8 __attribute__((ext_vector_type(8)));
typedef float f32x4 __attribute__((ext_vector_type(4)));
typedef unsigned long long u64;

__device__ __forceinline__ void astore_u32(unsigned* p, unsigned v) {
    __hip_atomic_store(p, v, __ATOMIC_RELAXED, __HIP_MEMORY_SCOPE_AGENT);
}

// fast activations: v_exp_f32 (2^x) + v_rcp_f32; rel err ~1e-6 (<< split-bf16 noise)
__device__ __forceinline__ float fsig(float x) {
    return __builtin_amdgcn_rcpf(1.f + __builtin_amdgcn_exp2f(-1.44269504f * x));
}
__device__ __forceinline__ float ftanh(float x) {
    return 1.f - 2.f * __builtin_amdgcn_rcpf(1.f + __builtin_amdgcn_exp2f(2.88539008f * x));
}

// split f32 -> (bf16 hi | bf16 lo) packed in u32 (hi in top 16, lo in bottom 16)
__device__ __forceinline__ unsigned pack_split(float x) {
    unsigned xb = __float_as_uint(x);
    unsigned hi = (xb + 0x7fffu + ((xb >> 16) & 1u)) & 0xffff0000u;
    float rest = x - __uint_as_float(hi);
    unsigned rb = __float_as_uint(rest);
    unsigned lo = (rb + 0x7fffu + ((rb >> 16) & 1u)) >> 16;
    return hi | (lo & 0xffffu);
}

// unpack 8 packed u32 (2x uint4) into hi-bf16x8 / lo-bf16x8 (r8-verified ordering)
__device__ __forceinline__ void unpack8(uint4 u0, uint4 u1, short8& hi, short8& lo) {
    union { uint4 u; short8 s; } H, L;
    H.u = make_uint4((u0.x >> 16) | (u0.y & 0xffff0000u),
                     (u0.z >> 16) | (u0.w & 0xffff0000u),
                     (u1.x >> 16) | (u1.y & 0xffff0000u),
                     (u1.z >> 16) | (u1.w & 0xffff0000u));
    L.u = make_uint4((u0.x & 0xffffu) | (u0.y << 16),
                     (u0.z & 0xffffu) | (u0.w << 16),
                     (u1.x & 0xffffu) | (u1.y << 16),
                     (u1.z & 0xffffu) | (u1.w << 16));
    hi = H.s; lo = L.s;
}

// ---------------- elementwise f32 -> packed split u32 ---------------------------
__global__ __launch_bounds__(256) void pack_kernel(
    const float* __restrict__ in, unsigned* __restrict__ out, int n)
{
    for (int i = blockIdx.x*256 + threadIdx.x; i < n; i += gridDim.x*256)
        out[i] = pack_split(in[i]);
}

// ---------------- MFMA split-bf16 GEMM: pre(4096, ncols) = W * B^T + bias ------
// (unchanged from r14 — verified)
__global__ __launch_bounds__(256) void gemm_mfma(
    const unsigned* __restrict__ Wpk, const float* __restrict__ Wf,
    const void* __restrict__ Bsrc, const float* __restrict__ bias,
    float* __restrict__ Cout, int K, int mode, int lo, int ncols)
{
    __shared__ __align__(16) unsigned As[4096];
    __shared__ __align__(16) unsigned Bs[4096];
    char* asb = (char*)As; char* bsb = (char*)Bs;
    const int m0 = blockIdx.y * 128;
    const int n0 = blockIdx.x * 128;
    const int dir = m0 >> 11;
    const int tid = threadIdx.x;
    const int w = tid >> 6;
    const int lane = tid & 63;
    const int dlt = lane & 15, gma = lane >> 4;
    const int mw = (w >> 1) * 64, nw = (w & 1) * 64;
    const int srow = tid >> 1;
    const int sh   = tid & 1;

    f32x4 acc[4][4];
#pragma unroll
    for (int mi = 0; mi < 4; ++mi)
#pragma unroll
        for (int ni = 0; ni < 4; ++ni) acc[mi][ni] = (f32x4){0.f,0.f,0.f,0.f};

    for (int k0 = 0; k0 < K; k0 += 32) {
        __syncthreads();
        {   // A tile
            unsigned v[16];
            if (Wpk) {
                const unsigned* ap = Wpk + (size_t)(m0 + srow)*K + k0 + sh*16;
                uint4 q0 = *(const uint4*)(ap);
                uint4 q1 = *(const uint4*)(ap + 4);
                uint4 q2 = *(const uint4*)(ap + 8);
                uint4 q3 = *(const uint4*)(ap + 12);
                v[0]=q0.x; v[1]=q0.y; v[2]=q0.z; v[3]=q0.w;
                v[4]=q1.x; v[5]=q1.y; v[6]=q1.z; v[7]=q1.w;
                v[8]=q2.x; v[9]=q2.y; v[10]=q2.z; v[11]=q2.w;
                v[12]=q3.x; v[13]=q3.y; v[14]=q3.z; v[15]=q3.w;
            } else {
                const float* ap = Wf + (size_t)(m0 + srow)*K + k0 + sh*16;
#pragma unroll
                for (int i = 0; i < 16; ++i) v[i] = pack_split(ap[i]);
            }
#pragma unroll
            for (int j = 0; j < 4; ++j) {
                int c = sh*4 + j;
                int byte = srow*128 + ((c ^ (srow & 7)) << 4);
                *(uint4*)(asb + byte) = make_uint4(v[4*j],v[4*j+1],v[4*j+2],v[4*j+3]);
            }
        }
        {   // B tile
            const int n = n0 + srow;
            const int bb2 = n & 63, tloc = n >> 6;
            const int t = dir ? (255 - lo - tloc) : (lo + tloc);
            unsigned v[16];
            if (mode == 0) {
                const float* bp = (const float*)Bsrc + ((size_t)bb2*T_ + t)*F0_ + k0 + sh*16;
#pragma unroll
                for (int i = 0; i < 16; ++i) v[i] = pack_split(bp[i]);
            } else {
                const unsigned* bp = (const unsigned*)Bsrc
                    + (size_t)t*(1024*64) + (size_t)(k0 + sh*16)*64 + bb2;
#pragma unroll
                for (int i = 0; i < 16; ++i) v[i] = bp[(size_t)i*64];
            }
#pragma unroll
            for (int j = 0; j < 4; ++j) {
                int c = sh*4 + j;
                int byte = srow*128 + ((c ^ (srow & 7)) << 4);
                *(uint4*)(bsb + byte) = make_uint4(v[4*j],v[4*j+1],v[4*j+2],v[4*j+3]);
            }
        }
        __syncthreads();

        short8 ah[4], al[4];
#pragma unroll
        for (int mi = 0; mi < 4; ++mi) {
            int base = (mw + mi*16 + dlt) * 128;
            uint4 u0 = *(const uint4*)(asb + base + (((gma*2    ) ^ (dlt & 7)) << 4));
            uint4 u1 = *(const uint4*)(asb + base + (((gma*2 + 1) ^ (dlt & 7)) << 4));
            unpack8(u0, u1, ah[mi], al[mi]);
        }
#pragma unroll
        for (int ni = 0; ni < 4; ++ni) {
            int base = (nw + ni*16 + dlt) * 128;
            uint4 u0 = *(const uint4*)(bsb + base + (((gma*2    ) ^ (dlt & 7)) << 4));
            uint4 u1 = *(const uint4*)(bsb + base + (((gma*2 + 1) ^ (dlt & 7)) << 4));
            short8 bh, bl;
            unpack8(u0, u1, bh, bl);
#pragma unroll
            for (int mi = 0; mi < 4; ++mi) {
                acc[mi][ni] = __builtin_amdgcn_mfma_f32_16x16x32_bf16(ah[mi], bh, acc[mi][ni], 0, 0, 0);
                acc[mi][ni] = __builtin_amdgcn_mfma_f32_16x16x32_bf16(ah[mi], bl, acc[mi][ni], 0, 0, 0);
                acc[mi][ni] = __builtin_amdgcn_mfma_f32_16x16x32_bf16(al[mi], bh, acc[mi][ni], 0, 0, 0);
            }
        }
    }

#pragma unroll
    for (int mi = 0; mi < 4; ++mi)
#pragma unroll
        for (int ni = 0; ni < 4; ++ni) {
            const int n = n0 + nw + ni*16 + dlt;
#pragma unroll
            for (int r = 0; r < 4; ++r) {
                const int m = m0 + mw + mi*16 + gma*4 + r;
                Cout[(size_t)m*ncols + n] = acc[mi][ni][r] + bias[m];
            }
        }
}

// ---------------- persistent bidirectional LSTM scan, wave-autonomous ----------
// 256 blocks = 2 dir x 32 kblk (16 k) x 4 bgrp (16 b); 256 threads = 4 mfma waves.
// NO barrier, NO in-loop syncthreads: per-(block,wave) FLAG (monotonic step count,
// own address -> no RMW serialization). Consumer wave polls its group's 128 flags
// with one coalesced 64-lane u64 atomic load + ballot. Producer orders h->flag
// with vmcnt(0). B operand read DIRECTLY from global (m89 fragment: 2 uint4 at
// hbig[bb*512 + kt*32 + gma*8]; 4 gma lanes cover a full 128B line). Rotating
// 32 buffers keep plain loads stale-free (each line read once per launch; reuse
// spans kernel boundary). LDS = W only (128K). Waves write exactly the W rows
// they read -> no cross-wave LDS dependency.
#define LDS_W_HI 0
#define LDS_W_LO 65536

__global__ __launch_bounds__(256, 1) void lstm_scan(
    const float* __restrict__ Whh,   // (2, 2048, 512)
    const float* __restrict__ pre,   // (4096, ncols)
    void* __restrict__ outbuf,       // (T_, 1024, B_) f32 or packed u32
    int packout,
    unsigned* __restrict__ hbig,     // [NBUF][2 dir][64 b][512 k] packed u32
    float* __restrict__ cbuf,        // [2 dir][512 k][64 b]
    unsigned* __restrict__ flags,    // [8 group][128] monotonic step counters
    int lo, int first, int fbase, int tcount, int ncols)
{
    extern __shared__ char smem[];   // 128K: W split hi/lo [64 m][512 j]
    const int bid  = blockIdx.x;
    const int dir  = bid >> 7;
    const int r7   = bid & 127;
    const int kblk = r7 >> 2;        // 0..31
    const int bgrp = r7 & 3;         // 0..3
    const int b0   = bgrp * 16;
    const int tid  = threadIdx.x;
    const int wid  = tid >> 6;       // 0..3
    const int lane = tid & 63;
    const int dlt  = lane & 15;
    const int gma  = lane >> 4;

    {   // ---- W prep (once): wave wid writes exactly rows [wid*16, wid*16+16) ----
        const int m  = tid >> 2;           // 0..63
        const int j0 = (tid & 3) * 128;    // 128 f32 per thread
        const int g = m & 3, kl = m >> 2;
        const float* wr = Whh + ((size_t)(dir*2048 + g*512 + kblk*16 + kl))*512 + j0;
#pragma unroll
        for (int seg = 0; seg < 8; ++seg) {
            unsigned hw[8], lw[8];
#pragma unroll
            for (int i = 0; i < 8; ++i) {
                unsigned q0 = pack_split(wr[seg*16 + 2*i]);
                unsigned q1 = pack_split(wr[seg*16 + 2*i + 1]);
                hw[i] = (q0 >> 16) | (q1 & 0xffff0000u);
                lw[i] = (q0 & 0xffffu) | (q1 << 16);
            }
            const int jb = (j0 + seg*16) * 2;
            const int of0 = (m << 10) + ((jb     ) ^ ((m & 7) << 4));
            const int of1 = (m << 10) + ((jb + 16) ^ ((m & 7) << 4));
            *(uint4*)(smem + LDS_W_HI + of0) = make_uint4(hw[0],hw[1],hw[2],hw[3]);
            *(uint4*)(smem + LDS_W_HI + of1) = make_uint4(hw[4],hw[5],hw[6],hw[7]);
            *(uint4*)(smem + LDS_W_LO + of0) = make_uint4(lw[0],lw[1],lw[2],lw[3]);
            *(uint4*)(smem + LDS_W_LO + of1) = make_uint4(lw[4],lw[5],lw[6],lw[7]);
        }
    }

    const int kg = kblk*16 + wid*4 + gma;   // this lane's k
    const int bb = b0 + dlt;                // this lane's b
    unsigned* gflags = flags + (((dir << 2) | bgrp) << 7);   // 128 u32, 512B
    const int myflag = kblk*4 + wid;

    float c = 0.f;
    if (first) {
        // h_{-1} = 0 in buffer NBUF-1: each lane zeros its own (kg, bb) slot
        astore_u32(hbig + ((size_t)(NBUF-1)*2 + dir)*32768 + (size_t)bb*512 + kg, 0u);
        asm volatile("s_waitcnt vmcnt(0)" ::: "memory");
        if (lane == 0) astore_u32(&gflags[myflag], (unsigned)(fbase + 1));
    } else {
        c = cbuf[(size_t)dir*32768 + (size_t)kg*64 + bb];
    }
    __syncthreads();   // one-time (W ready; harmless)

    const int arow = (wid*16 + dlt) << 10;
    const int axor = ((wid*16 + dlt) & 7) << 4;

    for (int s = 0; s < tcount; ++s) {
        const int v = lo + s;
        const int t = dir ? (255 - v) : v;
        const int ridx = (v + NBUF - 1) & (NBUF-1);
        const int widx = v & (NBUF-1);

        // early pre loads (independent of flags; hidden under poll)
        const size_t col = (size_t)s*64 + bb;
        float p0 = pre[((size_t)(dir*2048 +        kg))*ncols + col];
        float p1 = pre[((size_t)(dir*2048 +  512 + kg))*ncols + col];
        float p2 = pre[((size_t)(dir*2048 + 1024 + kg))*ncols + col];
        float p3 = pre[((size_t)(dir*2048 + 1536 + kg))*ncols + col];

        // ---- wave-local poll: all 128 group flags >= fbase+v+1 ----
        {
            const unsigned tgt = (unsigned)(fbase + v + 1);
            const u64* fp = (const u64*)gflags;
            while (true) {
                u64 f2 = __hip_atomic_load(&fp[lane], __ATOMIC_RELAXED, __HIP_MEMORY_SCOPE_AGENT);
                int ok = ((unsigned)f2 >= tgt) && ((unsigned)(f2 >> 32) >= tgt);
                if (__ballot(ok) == ~0ULL) break;
                __builtin_amdgcn_s_sleep(1);
            }
        }
        asm volatile("" ::: "memory");   // no B-load hoisting above the poll

        // ---- B operand: direct coalesced global loads (L2-shared) ----
        const uint4* hb4 = (const uint4*)(hbig + ((size_t)ridx*2 + dir)*32768)
                         + (size_t)bb*128 + 2*gma;
        uint4 bv0[16], bv1[16];
#pragma unroll
        for (int kt = 0; kt < 16; ++kt) {
            bv0[kt] = hb4[kt*8];
            bv1[kt] = hb4[kt*8 + 1];
        }

        f32x4 acc = {p0, p1, p2, p3};
#pragma unroll
        for (int kt = 0; kt < 16; ++kt) {
            const int jb  = (kt << 6) + (gma << 4);
            const int aof = arow + (jb ^ axor);
            short8 ah = *(const short8*)(smem + LDS_W_HI + aof);
            short8 al = *(const short8*)(smem + LDS_W_LO + aof);
            short8 bh, bl;
            unpack8(bv0[kt], bv1[kt], bh, bl);
            acc = __builtin_amdgcn_mfma_f32_16x16x32_bf16(ah, bh, acc, 0, 0, 0);
            acc = __builtin_amdgcn_mfma_f32_16x16x32_bf16(ah, bl, acc, 0, 0, 0);
            acc = __builtin_amdgcn_mfma_f32_16x16x32_bf16(al, bh, acc, 0, 0, 0);
        }

        float ig = fsig(acc[0]);
        float fg = fsig(acc[1]);
        float gg = ftanh(acc[2]);
        float og = fsig(acc[3]);
        c = fg * c + ig * gg;
        float h = og * ftanh(c);
        unsigned hpv = pack_split(h);

        // publish h -> drain -> flag -> (out/cbuf off critical path)
        astore_u32(hbig + ((size_t)widx*2 + dir)*32768 + (size_t)bb*512 + kg, hpv);
        asm volatile("s_waitcnt vmcnt(0)" ::: "memory");
        if (lane == 0) astore_u32(&gflags[myflag], (unsigned)(fbase + v + 2));
        const size_t oidx = ((size_t)t*1024 + dir*512 + kg)*64 + bb;
        if (packout) ((unsigned*)outbuf)[oidx] = hpv;
        else         ((float*)outbuf)[oidx]    = h;
        if (s == tcount-1) cbuf[(size_t)dir*32768 + (size_t)kg*64 + bb] = c;
    }
}

// ---------------- emissions (h1 f32) --------------------------------------------
__global__ __launch_bounds__(256) void emis_kernel(
    const float* __restrict__ h1, const float* __restrict__ Wout,
    const float* __restrict__ bout, float* __restrict__ em)
{
    const int s = blockIdx.x;
    const int tid = threadIdx.x;
    const int b = tid & 63;
    const int cl = tid >> 6;
    __shared__ float wl[32][128];
    float acc[8];
#pragma unroll
    for (int u = 0; u < 8; ++u) acc[u] = 0.f;
    const float* hp = h1 + (size_t)s * (1024*64);
    for (int f0 = 0; f0 < 1024; f0 += 128) {
        __syncthreads();
        for (int u = tid; u < 4096; u += 256) {
            int cc = u >> 7, ff = u & 127;
            wl[cc][ff] = Wout[(size_t)cc*1024 + f0 + ff];
        }
        __syncthreads();
        for (int ff = 0; ff < 128; ++ff) {
            float hv = hp[(size_t)(f0+ff)*64 + b];
#pragma unroll
            for (int u = 0; u < 8; ++u) acc[u] += hv * wl[cl + u*4][ff];
        }
    }
#pragma unroll
    for (int u = 0; u < 8; ++u) {
        int cc = cl + u*4;
        em[((size_t)b*T_ + s)*C_ + cc] = acc[u] + bout[cc];
    }
}

// ---------------- CRF Viterbi: half-wave split max + em prefetch ----------------
__global__ __launch_bounds__(64) void viterbi_kernel(
    const float* __restrict__ em, const float* __restrict__ start_t,
    const float* __restrict__ end_t, const float* __restrict__ trans,
    float* __restrict__ dout)
{
    const int b = blockIdx.x;
    const int l = threadIdx.x;
    const int j = l & 31;
    const int half = l >> 5;
    __shared__ float tr[C_*C_];
    __shared__ float sc[2][C_];
    __shared__ unsigned char hist[T_-1][C_];
    const float* emb = em + (size_t)b * T_ * C_;
    for (int i = l; i < C_*C_; i += 64) tr[i] = trans[i];
    if (l < C_) sc[0][l] = start_t[l] + emb[l];
    __syncthreads();

    float em_next = emb[C_ + j];
    for (int s = 1; s < T_; ++s) {
        const int cur = (s-1) & 1, nxt = s & 1;
        float em_cur = em_next;
        if (s + 1 < T_) em_next = emb[(size_t)(s+1)*C_ + j];
        float best = -3.4e38f; int bi = 0;
#pragma unroll
        for (int q = 0; q < 16; ++q) {
            const int i = half*16 + q;
            float v = sc[cur][i] + tr[i*C_ + j];
            if (v > best) { best = v; bi = i; }
        }
        float obest = __shfl_xor(best, 32);
        int   obi   = __shfl_xor(bi, 32);
        if (half == 0) { if (obest >  best) { best = obest; bi = obi; } }
        else           { if (obest >= best) { best = obest; bi = obi; } }
        if (half == 0) {
            sc[nxt][j] = best + em_cur;
            hist[s-1][j] = (unsigned char)bi;
        }
        __syncthreads();
    }
    if (l == 0) {
        const int cur = (T_-1) & 1;
        float best = -3.4e38f; int bi = 0;
        for (int i = 0; i < C_; ++i) {
            float v = sc[cur][i] + end_t[i];
            if (v > best) { best = v; bi = i; }
        }
        dout[(size_t)B_*T_ + b] = best;
        float* tout = dout + (size_t)b * T_;
        int tag = bi;
        tout[T_-1] = (float)tag;
        for (int s = T_-2; s >= 0; --s) {
            tag = hist[s][tag];
            tout[s] = (float)tag;
        }
    }
}

// ---------------- host launch ---------------------------------------------------
extern "C" void kernel_launch(void* const* d_in, const int* in_sizes, int n_in,
                              void* d_out, int out_size, void* d_ws, size_t ws_size,
                              hipStream_t stream) {
    const float* x    = (const float*)d_in[0];
    const float* Wih0 = (const float*)d_in[2];
    const float* Whh0 = (const float*)d_in[3];
    const float* b0   = (const float*)d_in[4];
    const float* Wih1 = (const float*)d_in[5];
    const float* Whh1 = (const float*)d_in[6];
    const float* b1   = (const float*)d_in[7];
    const float* Wout = (const float*)d_in[8];
    const float* bout = (const float*)d_in[9];
    const float* st   = (const float*)d_in[10];
    const float* en   = (const float*)d_in[11];
    const float* tr   = (const float*)d_in[12];
    float* dout = (float*)d_out;

    char* ws = (char*)d_ws;
    const size_t o_flg  = 0;                                   // 4 KiB (8 grp x 512B)
    const size_t o_cbuf = 4096;                                // 256 KiB
    const size_t o_hbig = o_cbuf + 262144;                     // 8 MiB (32 bufs)
    const size_t o_h0   = o_hbig + 8388608;                    // 64 MiB (packed u32)
    const size_t o_h1   = o_h0 + (size_t)67108864;             // 64 MiB (f32)
    const size_t o_pre  = o_h1 + (size_t)67108864;             // 16 or 32 MiB

    // ws-adaptive tiers: TC32+packW -> TC32 -> TC16
    int TCR; bool packW;
    const size_t base = o_pre;
    if      (ws_size >= base + 33554432ULL + 20971520ULL) { TCR = 32; packW = true;  }
    else if (ws_size >= base + 33554432ULL)               { TCR = 32; packW = false; }
    else                                                  { TCR = 16; packW = false; }
    const size_t presz = (size_t)4096 * TCR * 64 * 4;
    const size_t o_w0pk = o_pre + presz;
    const size_t o_w1pk = o_w0pk + 4194304;
    const int ncols = TCR * 64;
    const int nc = 256 / TCR;

    unsigned* flg  = (unsigned*)(ws + o_flg);
    float* cbuf    = (float*)(ws + o_cbuf);
    unsigned* hbig = (unsigned*)(ws + o_hbig);
    unsigned* h0pk = (unsigned*)(ws + o_h0);
    float* h1      = (float*)(ws + o_h1);
    float* pre     = (float*)(ws + o_pre);
    float* em      = (float*)(ws + o_pre);    // aliases pre (pre dead by emis time)
    unsigned* w0pk = packW ? (unsigned*)(ws + o_w0pk) : nullptr;
    unsigned* w1pk = packW ? (unsigned*)(ws + o_w1pk) : nullptr;

    hipMemsetAsync(flg, 0, 4096, stream);

    const int LDS_BYTES = 131072;
    hipFuncSetAttribute(reinterpret_cast<const void*>(lstm_scan),
                        hipFuncAttributeMaxDynamicSharedMemorySize, LDS_BYTES);

    if (packW) {
        pack_kernel<<<1024, 256, 0, stream>>>(Wih0, w0pk, 4096*256);
        pack_kernel<<<2048, 256, 0, stream>>>(Wih1, w1pk, 4096*1024);
    }

    dim3 gg(ncols/128, 32), bb(256);
    for (int ci = 0; ci < nc; ++ci) {
        int lo = ci * TCR;
        gemm_mfma<<<gg, bb, 0, stream>>>(w0pk, Wih0, x, b0, pre, F0_, 0, lo, ncols);
        lstm_scan<<<256, 256, LDS_BYTES, stream>>>(Whh0, pre, h0pk, 1, hbig, cbuf, flg,
                                                   lo, ci == 0 ? 1 : 0, 0, TCR, ncols);
    }
    for (int ci = 0; ci < nc; ++ci) {
        int lo = ci * TCR;
        gemm_mfma<<<gg, bb, 0, stream>>>(w1pk, Wih1, h0pk, b1, pre, 1024, 1, lo, ncols);
        lstm_scan<<<256, 256, LDS_BYTES, stream>>>(Whh1, pre, h1, 0, hbig, cbuf, flg,
                                                   lo, ci == 0 ? 1 : 0, 300, TCR, ncols);
    }
    emis_kernel<<<T_, bb, 0, stream>>>(h1, Wout, bout, em);
    viterbi_kernel<<<B_, 64, 0, stream>>>(em, st, en, tr, dout);
}

// Round 16
// 3919.655 us; speedup vs baseline: 1.0715x; 1.0715x over previous
//
#include <hip/hip_runtime.h>

#define B_   64
#define T_   256
#define H_   512
#define F0_  256
#define C_   32
#define NBUF 32

typedef short short8 __attribute__((ext_vector_type(8)));
typedef float f32x4 __attribute__((ext_vector_type(4)));
typedef unsigned long long u64;

__device__ __forceinline__ void astore_u32(unsigned* p, unsigned v) {
    __hip_atomic_store(p, v, __ATOMIC_RELAXED, __HIP_MEMORY_SCOPE_AGENT);
}

// fast activations: v_exp_f32 (2^x) + v_rcp_f32; rel err ~1e-6 (<< split-bf16 noise)
__device__ __forceinline__ float fsig(float x) {
    return __builtin_amdgcn_rcpf(1.f + __builtin_amdgcn_exp2f(-1.44269504f * x));
}
__device__ __forceinline__ float ftanh(float x) {
    return 1.f - 2.f * __builtin_amdgcn_rcpf(1.f + __builtin_amdgcn_exp2f(2.88539008f * x));
}

// split f32 -> (bf16 hi | bf16 lo) packed in u32 (hi in top 16, lo in bottom 16)
__device__ __forceinline__ unsigned pack_split(float x) {
    unsigned xb = __float_as_uint(x);
    unsigned hi = (xb + 0x7fffu + ((xb >> 16) & 1u)) & 0xffff0000u;
    float rest = x - __uint_as_float(hi);
    unsigned rb = __float_as_uint(rest);
    unsigned lo = (rb + 0x7fffu + ((rb >> 16) & 1u)) >> 16;
    return hi | (lo & 0xffffu);
}

// unpack 8 packed u32 (2x uint4) into hi-bf16x8 / lo-bf16x8 (r8-verified ordering)
__device__ __forceinline__ void unpack8(uint4 u0, uint4 u1, short8& hi, short8& lo) {
    union { uint4 u; short8 s; } H, L;
    H.u = make_uint4((u0.x >> 16) | (u0.y & 0xffff0000u),
                     (u0.z >> 16) | (u0.w & 0xffff0000u),
                     (u1.x >> 16) | (u1.y & 0xffff0000u),
                     (u1.z >> 16) | (u1.w & 0xffff0000u));
    L.u = make_uint4((u0.x & 0xffffu) | (u0.y << 16),
                     (u0.z & 0xffffu) | (u0.w << 16),
                     (u1.x & 0xffffu) | (u1.y << 16),
                     (u1.z & 0xffffu) | (u1.w << 16));
    hi = H.s; lo = L.s;
}

// ---------------- elementwise f32 -> packed split u32 ---------------------------
__global__ __launch_bounds__(256) void pack_kernel(
    const float* __restrict__ in, unsigned* __restrict__ out, int n)
{
    for (int i = blockIdx.x*256 + threadIdx.x; i < n; i += gridDim.x*256)
        out[i] = pack_split(in[i]);
}

// ---------------- MFMA split-bf16 GEMM: pre(4096, ncols) = W * B^T + bias ------
// (unchanged from r14 — verified)
__global__ __launch_bounds__(256) void gemm_mfma(
    const unsigned* __restrict__ Wpk, const float* __restrict__ Wf,
    const void* __restrict__ Bsrc, const float* __restrict__ bias,
    float* __restrict__ Cout, int K, int mode, int lo, int ncols)
{
    __shared__ __align__(16) unsigned As[4096];
    __shared__ __align__(16) unsigned Bs[4096];
    char* asb = (char*)As; char* bsb = (char*)Bs;
    const int m0 = blockIdx.y * 128;
    const int n0 = blockIdx.x * 128;
    const int dir = m0 >> 11;
    const int tid = threadIdx.x;
    const int w = tid >> 6;
    const int lane = tid & 63;
    const int dlt = lane & 15, gma = lane >> 4;
    const int mw = (w >> 1) * 64, nw = (w & 1) * 64;
    const int srow = tid >> 1;
    const int sh   = tid & 1;

    f32x4 acc[4][4];
#pragma unroll
    for (int mi = 0; mi < 4; ++mi)
#pragma unroll
        for (int ni = 0; ni < 4; ++ni) acc[mi][ni] = (f32x4){0.f,0.f,0.f,0.f};

    for (int k0 = 0; k0 < K; k0 += 32) {
        __syncthreads();
        {   // A tile
            unsigned v[16];
            if (Wpk) {
                const unsigned* ap = Wpk + (size_t)(m0 + srow)*K + k0 + sh*16;
                uint4 q0 = *(const uint4*)(ap);
                uint4 q1 = *(const uint4*)(ap + 4);
                uint4 q2 = *(const uint4*)(ap + 8);
                uint4 q3 = *(const uint4*)(ap + 12);
                v[0]=q0.x; v[1]=q0.y; v[2]=q0.z; v[3]=q0.w;
                v[4]=q1.x; v[5]=q1.y; v[6]=q1.z; v[7]=q1.w;
                v[8]=q2.x; v[9]=q2.y; v[10]=q2.z; v[11]=q2.w;
                v[12]=q3.x; v[13]=q3.y; v[14]=q3.z; v[15]=q3.w;
            } else {
                const float* ap = Wf + (size_t)(m0 + srow)*K + k0 + sh*16;
#pragma unroll
                for (int i = 0; i < 16; ++i) v[i] = pack_split(ap[i]);
            }
#pragma unroll
            for (int j = 0; j < 4; ++j) {
                int c = sh*4 + j;
                int byte = srow*128 + ((c ^ (srow & 7)) << 4);
                *(uint4*)(asb + byte) = make_uint4(v[4*j],v[4*j+1],v[4*j+2],v[4*j+3]);
            }
        }
        {   // B tile
            const int n = n0 + srow;
            const int bb2 = n & 63, tloc = n >> 6;
            const int t = dir ? (255 - lo - tloc) : (lo + tloc);
            unsigned v[16];
            if (mode == 0) {
                const float* bp = (const float*)Bsrc + ((size_t)bb2*T_ + t)*F0_ + k0 + sh*16;
#pragma unroll
                for (int i = 0; i < 16; ++i) v[i] = pack_split(bp[i]);
            } else {
                const unsigned* bp = (const unsigned*)Bsrc
                    + (size_t)t*(1024*64) + (size_t)(k0 + sh*16)*64 + bb2;
#pragma unroll
                for (int i = 0; i < 16; ++i) v[i] = bp[(size_t)i*64];
            }
#pragma unroll
            for (int j = 0; j < 4; ++j) {
                int c = sh*4 + j;
                int byte = srow*128 + ((c ^ (srow & 7)) << 4);
                *(uint4*)(bsb + byte) = make_uint4(v[4*j],v[4*j+1],v[4*j+2],v[4*j+3]);
            }
        }
        __syncthreads();

        short8 ah[4], al[4];
#pragma unroll
        for (int mi = 0; mi < 4; ++mi) {
            int base = (mw + mi*16 + dlt) * 128;
            uint4 u0 = *(const uint4*)(asb + base + (((gma*2    ) ^ (dlt & 7)) << 4));
            uint4 u1 = *(const uint4*)(asb + base + (((gma*2 + 1) ^ (dlt & 7)) << 4));
            unpack8(u0, u1, ah[mi], al[mi]);
        }
#pragma unroll
        for (int ni = 0; ni < 4; ++ni) {
            int base = (nw + ni*16 + dlt) * 128;
            uint4 u0 = *(const uint4*)(bsb + base + (((gma*2    ) ^ (dlt & 7)) << 4));
            uint4 u1 = *(const uint4*)(bsb + base + (((gma*2 + 1) ^ (dlt & 7)) << 4));
            short8 bh, bl;
            unpack8(u0, u1, bh, bl);
#pragma unroll
            for (int mi = 0; mi < 4; ++mi) {
                acc[mi][ni] = __builtin_amdgcn_mfma_f32_16x16x32_bf16(ah[mi], bh, acc[mi][ni], 0, 0, 0);
                acc[mi][ni] = __builtin_amdgcn_mfma_f32_16x16x32_bf16(ah[mi], bl, acc[mi][ni], 0, 0, 0);
                acc[mi][ni] = __builtin_amdgcn_mfma_f32_16x16x32_bf16(al[mi], bh, acc[mi][ni], 0, 0, 0);
            }
        }
    }

#pragma unroll
    for (int mi = 0; mi < 4; ++mi)
#pragma unroll
        for (int ni = 0; ni < 4; ++ni) {
            const int n = n0 + nw + ni*16 + dlt;
#pragma unroll
            for (int r = 0; r < 4; ++r) {
                const int m = m0 + mw + mi*16 + gma*4 + r;
                Cout[(size_t)m*ncols + n] = acc[mi][ni][r] + bias[m];
            }
        }
}

// ---------------- persistent bidirectional LSTM scan, MFMA split-bf16 ----------
// r14 structure (512 threads, 2 dir x 32 kblk x 4 bgrp, LDS B-staging, rotating
// 32 h-buffers, out-store off critical path, fast activations). ONE change:
// counting barrier (32 serialized RMWs/step) -> per-(block,wave) FLAGS.
// Publish order: h (sc1 store) -> vmcnt(0) -> wave flag (own address, no RMW).
// Sync: wave 0 polls all 128 group flags via coalesced u64 atomic loads +
// ballot; __syncthreads releases the block.
#define LDS_W_HI 0
#define LDS_W_LO 65536
#define LDS_B    131072

__global__ __launch_bounds__(512, 1) void lstm_scan(
    const float* __restrict__ Whh,   // (2, 2048, 512)
    const float* __restrict__ pre,   // (4096, ncols)
    void* __restrict__ outbuf,       // (T_, 1024, B_) f32 or packed u32
    int packout,
    unsigned* __restrict__ hbig,     // [NBUF][2 dir][64 b][512 k] packed u32
    float* __restrict__ cbuf,        // [2 dir][512 k][64 b]
    unsigned* __restrict__ flags,    // [8 group][128] monotonic step counters
    int lo, int first, int fbase, int tcount, int ncols)
{
    extern __shared__ char smem[];
    const int bid  = blockIdx.x;
    const int dir  = bid >> 7;
    const int r7   = bid & 127;
    const int kblk = r7 >> 2;        // 0..31
    const int bgrp = r7 & 3;         // 0..3
    const int b0   = bgrp * 16;
    const int tid  = threadIdx.x;
    const int wid  = tid >> 6;       // 0..7; waves 0-3 mfma
    const int lane = tid & 63;
    const int dlt  = lane & 15;
    const int gma  = lane >> 4;

    {   // ---- W prep (once): 64 m-rows (m = kl*4+g) x 512 j, split ----
        const int m  = tid >> 3;
        const int j0 = (tid & 7) * 64;
        const int g = m & 3, kl = m >> 2;
        const float* wr = Whh + ((size_t)(dir*2048 + g*512 + kblk*16 + kl))*512 + j0;
#pragma unroll
        for (int seg = 0; seg < 4; ++seg) {
            unsigned hw[8], lw[8];
#pragma unroll
            for (int i = 0; i < 8; ++i) {
                unsigned q0 = pack_split(wr[seg*16 + 2*i]);
                unsigned q1 = pack_split(wr[seg*16 + 2*i + 1]);
                hw[i] = (q0 >> 16) | (q1 & 0xffff0000u);
                lw[i] = (q0 & 0xffffu) | (q1 << 16);
            }
            const int jb = (j0 + seg*16) * 2;
            const int of0 = (m << 10) + ((jb     ) ^ ((m & 7) << 4));
            const int of1 = (m << 10) + ((jb + 16) ^ ((m & 7) << 4));
            *(uint4*)(smem + LDS_W_HI + of0) = make_uint4(hw[0],hw[1],hw[2],hw[3]);
            *(uint4*)(smem + LDS_W_HI + of1) = make_uint4(hw[4],hw[5],hw[6],hw[7]);
            *(uint4*)(smem + LDS_W_LO + of0) = make_uint4(lw[0],lw[1],lw[2],lw[3]);
            *(uint4*)(smem + LDS_W_LO + of1) = make_uint4(lw[4],lw[5],lw[6],lw[7]);
        }
    }

    const int kg = kblk*16 + wid*4 + gma;   // this lane's k (mfma waves, wid<4)
    const int bb = b0 + dlt;                // this lane's b
    unsigned* gflags = flags + (((dir << 2) | bgrp) << 7);   // 128 u32 = 512 B
    const int myflag = kblk*4 + wid;                          // wid<4 only

    float c = 0.f;
    if (first) {
        // h_{-1} = 0 in buffer NBUF-1: mfma lanes zero their own (kg, bb) slot
        if (wid < 4) {
            astore_u32(hbig + ((size_t)(NBUF-1)*2 + dir)*32768 + (size_t)bb*512 + kg, 0u);
            asm volatile("s_waitcnt vmcnt(0)" ::: "memory");
            if (lane == 0) astore_u32(&gflags[myflag], (unsigned)(fbase + 1));
        }
    } else if (wid < 4) {
        c = cbuf[(size_t)dir*32768 + (size_t)kg*64 + bb];
    }
    asm volatile("s_waitcnt vmcnt(0)" ::: "memory");
    __syncthreads();

    const int arow = (wid*16 + dlt) << 10;
    const int axor = ((wid*16 + dlt) & 7) << 4;

    for (int s = 0; s < tcount; ++s) {
        const int v = lo + s;
        const int t = dir ? (255 - v) : v;
        const int ridx = (v + NBUF - 1) & (NBUF-1);   // buffer holding h_{v-1}
        const int widx = v & (NBUF-1);                // buffer to publish h_v

        float p0, p1, p2, p3;
        if (wid < 4) {
            const size_t col = (size_t)s*64 + bb;
            p0 = pre[((size_t)(dir*2048 +        kg))*ncols + col];
            p1 = pre[((size_t)(dir*2048 +  512 + kg))*ncols + col];
            p2 = pre[((size_t)(dir*2048 + 1024 + kg))*ncols + col];
            p3 = pre[((size_t)(dir*2048 + 1536 + kg))*ncols + col];
        }

        // ---- sync: wave 0 polls all 128 group flags (no RMW anywhere) ----
        if (wid == 0) {
            const unsigned tgt = (unsigned)(fbase + v + 1);
            const u64* fp = (const u64*)gflags;
            while (true) {
                u64 f2 = __hip_atomic_load(&fp[lane], __ATOMIC_RELAXED, __HIP_MEMORY_SCOPE_AGENT);
                int ok = ((unsigned)f2 >= tgt) && ((unsigned)(f2 >> 32) >= tgt);
                if (__ballot(ok) == ~0ULL) break;
                __builtin_amdgcn_s_sleep(1);
            }
        }
        __syncthreads();                               // release block; LDS_B safe to overwrite

        // ---- stage h_{v-1}[all k][b0..b0+16): PLAIN uint4 loads (L2-cached) ----
        const uint4* src4 = (const uint4*)(hbig + ((size_t)ridx*2 + dir)*32768);
#pragma unroll
        for (int i = 0; i < 4; ++i) {
            const int cc = i*512 + tid;
            const int bl = cc >> 7;
            const int jc = cc & 127;
            uint4 vv = src4[(size_t)(b0 + bl)*128 + jc];
            *(uint4*)(smem + LDS_B + jc*256 + ((bl ^ (jc & 7)) << 4)) = vv;
        }
        __syncthreads();

        // ---- mfma K-loop + epilogue (waves 0-3) ----
        if (wid < 4) {
            f32x4 acc = {p0, p1, p2, p3};
            const int boff0 = (2*gma)*256   + ((dlt ^ (2*gma    )) << 4);
            const int boff1 = (2*gma+1)*256 + ((dlt ^ (2*gma + 1)) << 4);
#pragma unroll
            for (int kt = 0; kt < 16; ++kt) {
                const int jb  = (kt << 6) + (gma << 4);
                const int aof = arow + (jb ^ axor);
                short8 ah = *(const short8*)(smem + LDS_W_HI + aof);
                short8 al = *(const short8*)(smem + LDS_W_LO + aof);
                uint4 u0 = *(const uint4*)(smem + LDS_B + boff0 + (kt << 11));
                uint4 u1 = *(const uint4*)(smem + LDS_B + boff1 + (kt << 11));
                short8 bh, bl;
                unpack8(u0, u1, bh, bl);
                acc = __builtin_amdgcn_mfma_f32_16x16x32_bf16(ah, bh, acc, 0, 0, 0);
                acc = __builtin_amdgcn_mfma_f32_16x16x32_bf16(ah, bl, acc, 0, 0, 0);
                acc = __builtin_amdgcn_mfma_f32_16x16x32_bf16(al, bh, acc, 0, 0, 0);
            }
            float ig = fsig(acc[0]);
            float fg = fsig(acc[1]);
            float gg = ftanh(acc[2]);
            float og = fsig(acc[3]);
            c = fg * c + ig * gg;
            float h = og * ftanh(c);
            unsigned hpv = pack_split(h);
            // publish -> drain -> flag -> (out/cbuf off critical path)
            astore_u32(hbig + ((size_t)widx*2 + dir)*32768 + (size_t)bb*512 + kg, hpv);
            asm volatile("s_waitcnt vmcnt(0)" ::: "memory");
            if (lane == 0) astore_u32(&gflags[myflag], (unsigned)(fbase + v + 2));
            const size_t oidx = ((size_t)t*1024 + dir*512 + kg)*64 + bb;
            if (packout) ((unsigned*)outbuf)[oidx] = hpv;
            else         ((float*)outbuf)[oidx]    = h;
            if (s == tcount-1) cbuf[(size_t)dir*32768 + (size_t)kg*64 + bb] = c;
        }
    }
}

// ---------------- emissions (h1 f32) --------------------------------------------
__global__ __launch_bounds__(256) void emis_kernel(
    const float* __restrict__ h1, const float* __restrict__ Wout,
    const float* __restrict__ bout, float* __restrict__ em)
{
    const int s = blockIdx.x;
    const int tid = threadIdx.x;
    const int b = tid & 63;
    const int cl = tid >> 6;
    __shared__ float wl[32][128];
    float acc[8];
#pragma unroll
    for (int u = 0; u < 8; ++u) acc[u] = 0.f;
    const float* hp = h1 + (size_t)s * (1024*64);
    for (int f0 = 0; f0 < 1024; f0 += 128) {
        __syncthreads();
        for (int u = tid; u < 4096; u += 256) {
            int cc = u >> 7, ff = u & 127;
            wl[cc][ff] = Wout[(size_t)cc*1024 + f0 + ff];
        }
        __syncthreads();
        for (int ff = 0; ff < 128; ++ff) {
            float hv = hp[(size_t)(f0+ff)*64 + b];
#pragma unroll
            for (int u = 0; u < 8; ++u) acc[u] += hv * wl[cl + u*4][ff];
        }
    }
#pragma unroll
    for (int u = 0; u < 8; ++u) {
        int cc = cl + u*4;
        em[((size_t)b*T_ + s)*C_ + cc] = acc[u] + bout[cc];
    }
}

// ---------------- CRF Viterbi: half-wave split max + em prefetch ----------------
__global__ __launch_bounds__(64) void viterbi_kernel(
    const float* __restrict__ em, const float* __restrict__ start_t,
    const float* __restrict__ end_t, const float* __restrict__ trans,
    float* __restrict__ dout)
{
    const int b = blockIdx.x;
    const int l = threadIdx.x;
    const int j = l & 31;
    const int half = l >> 5;
    __shared__ float tr[C_*C_];
    __shared__ float sc[2][C_];
    __shared__ unsigned char hist[T_-1][C_];
    const float* emb = em + (size_t)b * T_ * C_;
    for (int i = l; i < C_*C_; i += 64) tr[i] = trans[i];
    if (l < C_) sc[0][l] = start_t[l] + emb[l];
    __syncthreads();

    float em_next = emb[C_ + j];
    for (int s = 1; s < T_; ++s) {
        const int cur = (s-1) & 1, nxt = s & 1;
        float em_cur = em_next;
        if (s + 1 < T_) em_next = emb[(size_t)(s+1)*C_ + j];
        float best = -3.4e38f; int bi = 0;
#pragma unroll
        for (int q = 0; q < 16; ++q) {
            const int i = half*16 + q;
            float v = sc[cur][i] + tr[i*C_ + j];
            if (v > best) { best = v; bi = i; }
        }
        float obest = __shfl_xor(best, 32);
        int   obi   = __shfl_xor(bi, 32);
        if (half == 0) { if (obest >  best) { best = obest; bi = obi; } }
        else           { if (obest >= best) { best = obest; bi = obi; } }
        if (half == 0) {
            sc[nxt][j] = best + em_cur;
            hist[s-1][j] = (unsigned char)bi;
        }
        __syncthreads();
    }
    if (l == 0) {
        const int cur = (T_-1) & 1;
        float best = -3.4e38f; int bi = 0;
        for (int i = 0; i < C_; ++i) {
            float v = sc[cur][i] + end_t[i];
            if (v > best) { best = v; bi = i; }
        }
        dout[(size_t)B_*T_ + b] = best;
        float* tout = dout + (size_t)b * T_;
        int tag = bi;
        tout[T_-1] = (float)tag;
        for (int s = T_-2; s >= 0; --s) {
            tag = hist[s][tag];
            tout[s] = (float)tag;
        }
    }
}

// ---------------- host launch ---------------------------------------------------
extern "C" void kernel_launch(void* const* d_in, const int* in_sizes, int n_in,
                              void* d_out, int out_size, void* d_ws, size_t ws_size,
                              hipStream_t stream) {
    const float* x    = (const float*)d_in[0];
    const float* Wih0 = (const float*)d_in[2];
    const float* Whh0 = (const float*)d_in[3];
    const float* b0   = (const float*)d_in[4];
    const float* Wih1 = (const float*)d_in[5];
    const float* Whh1 = (const float*)d_in[6];
    const float* b1   = (const float*)d_in[7];
    const float* Wout = (const float*)d_in[8];
    const float* bout = (const float*)d_in[9];
    const float* st   = (const float*)d_in[10];
    const float* en   = (const float*)d_in[11];
    const float* tr   = (const float*)d_in[12];
    float* dout = (float*)d_out;

    char* ws = (char*)d_ws;
    const size_t o_flg  = 0;                                   // 4 KiB (8 grp x 512B)
    const size_t o_cbuf = 4096;                                // 256 KiB
    const size_t o_hbig = o_cbuf + 262144;                     // 8 MiB (32 bufs)
    const size_t o_h0   = o_hbig + 8388608;                    // 64 MiB (packed u32)
    const size_t o_h1   = o_h0 + (size_t)67108864;             // 64 MiB (f32)
    const size_t o_pre  = o_h1 + (size_t)67108864;             // 16 or 32 MiB

    // ws-adaptive tiers: TC32+packW -> TC32 -> TC16
    int TCR; bool packW;
    const size_t base = o_pre;
    if      (ws_size >= base + 33554432ULL + 20971520ULL) { TCR = 32; packW = true;  }
    else if (ws_size >= base + 33554432ULL)               { TCR = 32; packW = false; }
    else                                                  { TCR = 16; packW = false; }
    const size_t presz = (size_t)4096 * TCR * 64 * 4;
    const size_t o_w0pk = o_pre + presz;
    const size_t o_w1pk = o_w0pk + 4194304;
    const int ncols = TCR * 64;
    const int nc = 256 / TCR;

    unsigned* flg  = (unsigned*)(ws + o_flg);
    float* cbuf    = (float*)(ws + o_cbuf);
    unsigned* hbig = (unsigned*)(ws + o_hbig);
    unsigned* h0pk = (unsigned*)(ws + o_h0);
    float* h1      = (float*)(ws + o_h1);
    float* pre     = (float*)(ws + o_pre);
    float* em      = (float*)(ws + o_pre);    // aliases pre (pre dead by emis time)
    unsigned* w0pk = packW ? (unsigned*)(ws + o_w0pk) : nullptr;
    unsigned* w1pk = packW ? (unsigned*)(ws + o_w1pk) : nullptr;

    hipMemsetAsync(flg, 0, 4096, stream);

    const int LDS_BYTES = 163840;
    hipFuncSetAttribute(reinterpret_cast<const void*>(lstm_scan),
                        hipFuncAttributeMaxDynamicSharedMemorySize, LDS_BYTES);

    if (packW) {
        pack_kernel<<<1024, 256, 0, stream>>>(Wih0, w0pk, 4096*256);
        pack_kernel<<<2048, 256, 0, stream>>>(Wih1, w1pk, 4096*1024);
    }

    dim3 gg(ncols/128, 32), bb(256);
    for (int ci = 0; ci < nc; ++ci) {
        int lo = ci * TCR;
        gemm_mfma<<<gg, bb, 0, stream>>>(w0pk, Wih0, x, b0, pre, F0_, 0, lo, ncols);
        lstm_scan<<<256, 512, LDS_BYTES, stream>>>(Whh0, pre, h0pk, 1, hbig, cbuf, flg,
                                                   lo, ci == 0 ? 1 : 0, 0, TCR, ncols);
    }
    for (int ci = 0; ci < nc; ++ci) {
        int lo = ci * TCR;
        gemm_mfma<<<gg, bb, 0, stream>>>(w1pk, Wih1, h0pk, b1, pre, 1024, 1, lo, ncols);
        lstm_scan<<<256, 512, LDS_BYTES, stream>>>(Whh1, pre, h1, 0, hbig, cbuf, flg,
                                                   lo, ci == 0 ? 1 : 0, 300, TCR, ncols);
    }
    emis_kernel<<<T_, bb, 0, stream>>>(h1, Wout, bout, em);
    viterbi_kernel<<<B_, 64, 0, stream>>>(em, st, en, tr, dout);
}

// Round 17
// 3540.987 us; speedup vs baseline: 1.1861x; 1.1069x over previous
//
#include <hip/hip_runtime.h>

#define B_   64
#define T_   256
#define H_   512
#define F0_  256
#define C_   32
#define NBUF 32

typedef short short8 __attribute__((ext_vector_type(8)));
typedef float f32x4 __attribute__((ext_vector_type(4)));
typedef unsigned long long u64;

__device__ __forceinline__ void astore_u32(unsigned* p, unsigned v) {
    __hip_atomic_store(p, v, __ATOMIC_RELAXED, __HIP_MEMORY_SCOPE_AGENT);
}

// fast activations: v_exp_f32 (2^x) + v_rcp_f32; rel err ~1e-6 (<< split-bf16 noise)
__device__ __forceinline__ float fsig(float x) {
    return __builtin_amdgcn_rcpf(1.f + __builtin_amdgcn_exp2f(-1.44269504f * x));
}
__device__ __forceinline__ float ftanh(float x) {
    return 1.f - 2.f * __builtin_amdgcn_rcpf(1.f + __builtin_amdgcn_exp2f(2.88539008f * x));
}

// split f32 -> (bf16 hi | bf16 lo) packed in u32 (hi in top 16, lo in bottom 16)
__device__ __forceinline__ unsigned pack_split(float x) {
    unsigned xb = __float_as_uint(x);
    unsigned hi = (xb + 0x7fffu + ((xb >> 16) & 1u)) & 0xffff0000u;
    float rest = x - __uint_as_float(hi);
    unsigned rb = __float_as_uint(rest);
    unsigned lo = (rb + 0x7fffu + ((rb >> 16) & 1u)) >> 16;
    return hi | (lo & 0xffffu);
}

// unpack 8 packed u32 (2x uint4) into hi-bf16x8 / lo-bf16x8 (r8-verified ordering)
__device__ __forceinline__ void unpack8(uint4 u0, uint4 u1, short8& hi, short8& lo) {
    union { uint4 u; short8 s; } H, L;
    H.u = make_uint4((u0.x >> 16) | (u0.y & 0xffff0000u),
                     (u0.z >> 16) | (u0.w & 0xffff0000u),
                     (u1.x >> 16) | (u1.y & 0xffff0000u),
                     (u1.z >> 16) | (u1.w & 0xffff0000u));
    L.u = make_uint4((u0.x & 0xffffu) | (u0.y << 16),
                     (u0.z & 0xffffu) | (u0.w << 16),
                     (u1.x & 0xffffu) | (u1.y << 16),
                     (u1.z & 0xffffu) | (u1.w << 16));
    hi = H.s; lo = L.s;
}

// ---------------- elementwise f32 -> packed split u32 ---------------------------
__global__ __launch_bounds__(256) void pack_kernel(
    const float* __restrict__ in, unsigned* __restrict__ out, int n)
{
    for (int i = blockIdx.x*256 + threadIdx.x; i < n; i += gridDim.x*256)
        out[i] = pack_split(in[i]);
}

// ---------------- MFMA split-bf16 GEMM: pre(4096, ncols) = W * B^T + bias ------
__global__ __launch_bounds__(256) void gemm_mfma(
    const unsigned* __restrict__ Wpk, const float* __restrict__ Wf,
    const void* __restrict__ Bsrc, const float* __restrict__ bias,
    float* __restrict__ Cout, int K, int mode, int lo, int ncols)
{
    __shared__ __align__(16) unsigned As[4096];
    __shared__ __align__(16) unsigned Bs[4096];
    char* asb = (char*)As; char* bsb = (char*)Bs;
    const int m0 = blockIdx.y * 128;
    const int n0 = blockIdx.x * 128;
    const int dir = m0 >> 11;
    const int tid = threadIdx.x;
    const int w = tid >> 6;
    const int lane = tid & 63;
    const int dlt = lane & 15, gma = lane >> 4;
    const int mw = (w >> 1) * 64, nw = (w & 1) * 64;
    const int srow = tid >> 1;
    const int sh   = tid & 1;

    f32x4 acc[4][4];
#pragma unroll
    for (int mi = 0; mi < 4; ++mi)
#pragma unroll
        for (int ni = 0; ni < 4; ++ni) acc[mi][ni] = (f32x4){0.f,0.f,0.f,0.f};

    for (int k0 = 0; k0 < K; k0 += 32) {
        __syncthreads();
        {   // A tile
            unsigned v[16];
            if (Wpk) {
                const unsigned* ap = Wpk + (size_t)(m0 + srow)*K + k0 + sh*16;
                uint4 q0 = *(const uint4*)(ap);
                uint4 q1 = *(const uint4*)(ap + 4);
                uint4 q2 = *(const uint4*)(ap + 8);
                uint4 q3 = *(const uint4*)(ap + 12);
                v[0]=q0.x; v[1]=q0.y; v[2]=q0.z; v[3]=q0.w;
                v[4]=q1.x; v[5]=q1.y; v[6]=q1.z; v[7]=q1.w;
                v[8]=q2.x; v[9]=q2.y; v[10]=q2.z; v[11]=q2.w;
                v[12]=q3.x; v[13]=q3.y; v[14]=q3.z; v[15]=q3.w;
            } else {
                const float* ap = Wf + (size_t)(m0 + srow)*K + k0 + sh*16;
#pragma unroll
                for (int i = 0; i < 16; ++i) v[i] = pack_split(ap[i]);
            }
#pragma unroll
            for (int j = 0; j < 4; ++j) {
                int c = sh*4 + j;
                int byte = srow*128 + ((c ^ (srow & 7)) << 4);
                *(uint4*)(asb + byte) = make_uint4(v[4*j],v[4*j+1],v[4*j+2],v[4*j+3]);
            }
        }
        {   // B tile
            const int n = n0 + srow;
            const int bb2 = n & 63, tloc = n >> 6;
            const int t = dir ? (255 - lo - tloc) : (lo + tloc);
            unsigned v[16];
            if (mode == 0) {
                const float* bp = (const float*)Bsrc + ((size_t)bb2*T_ + t)*F0_ + k0 + sh*16;
#pragma unroll
                for (int i = 0; i < 16; ++i) v[i] = pack_split(bp[i]);
            } else {
                const unsigned* bp = (const unsigned*)Bsrc
                    + (size_t)t*(1024*64) + (size_t)(k0 + sh*16)*64 + bb2;
#pragma unroll
                for (int i = 0; i < 16; ++i) v[i] = bp[(size_t)i*64];
            }
#pragma unroll
            for (int j = 0; j < 4; ++j) {
                int c = sh*4 + j;
                int byte = srow*128 + ((c ^ (srow & 7)) << 4);
                *(uint4*)(bsb + byte) = make_uint4(v[4*j],v[4*j+1],v[4*j+2],v[4*j+3]);
            }
        }
        __syncthreads();

        short8 ah[4], al[4];
#pragma unroll
        for (int mi = 0; mi < 4; ++mi) {
            int base = (mw + mi*16 + dlt) * 128;
            uint4 u0 = *(const uint4*)(asb + base + (((gma*2    ) ^ (dlt & 7)) << 4));
            uint4 u1 = *(const uint4*)(asb + base + (((gma*2 + 1) ^ (dlt & 7)) << 4));
            unpack8(u0, u1, ah[mi], al[mi]);
        }
#pragma unroll
        for (int ni = 0; ni < 4; ++ni) {
            int base = (nw + ni*16 + dlt) * 128;
            uint4 u0 = *(const uint4*)(bsb + base + (((gma*2    ) ^ (dlt & 7)) << 4));
            uint4 u1 = *(const uint4*)(bsb + base + (((gma*2 + 1) ^ (dlt & 7)) << 4));
            short8 bh, bl;
            unpack8(u0, u1, bh, bl);
#pragma unroll
            for (int mi = 0; mi < 4; ++mi) {
                acc[mi][ni] = __builtin_amdgcn_mfma_f32_16x16x32_bf16(ah[mi], bh, acc[mi][ni], 0, 0, 0);
                acc[mi][ni] = __builtin_amdgcn_mfma_f32_16x16x32_bf16(ah[mi], bl, acc[mi][ni], 0, 0, 0);
                acc[mi][ni] = __builtin_amdgcn_mfma_f32_16x16x32_bf16(al[mi], bh, acc[mi][ni], 0, 0, 0);
            }
        }
    }

#pragma unroll
    for (int mi = 0; mi < 4; ++mi)
#pragma unroll
        for (int ni = 0; ni < 4; ++ni) {
            const int n = n0 + nw + ni*16 + dlt;
#pragma unroll
            for (int r = 0; r < 4; ++r) {
                const int m = m0 + mw + mi*16 + gma*4 + r;
                Cout[(size_t)m*ncols + n] = acc[mi][ni][r] + bias[m];
            }
        }
}

// ---------------- persistent bidirectional LSTM scan, MFMA split-bf16 ----------
// r14 structure EXACT (512 threads, 2 dir x 32 kblk x 4 bgrp, LDS B-staging,
// rotating 32 h-buffers, out-store after publish drain, fast activations).
// ONE isolated change: group counting barrier split into 4 sub-counters
// (block kblk&3 -> own line; 8 serialized RMWs instead of 32). Wave 0
// lanes 0-3 poll the 4 dwords + ballot; __syncthreads releases block.
#define LDS_W_HI 0
#define LDS_W_LO 65536
#define LDS_B    131072

__global__ __launch_bounds__(512, 1) void lstm_scan(
    const float* __restrict__ Whh,   // (2, 2048, 512)
    const float* __restrict__ pre,   // (4096, ncols)
    void* __restrict__ outbuf,       // (T_, 1024, B_) f32 or packed u32
    int packout,
    unsigned* __restrict__ hbig,     // [NBUF][2 dir][64 b][512 k] packed u32
    float* __restrict__ cbuf,        // [2 dir][512 k][64 b]
    unsigned* __restrict__ bar,      // [8 group][128] : 4 sub-counters at +0,32,64,96
    int lo, int first, unsigned tgt0, int tcount, int ncols)
{
    extern __shared__ char smem[];
    const int bid  = blockIdx.x;
    const int dir  = bid >> 7;
    const int r7   = bid & 127;
    const int kblk = r7 >> 2;        // 0..31
    const int bgrp = r7 & 3;         // 0..3
    const int b0   = bgrp * 16;
    const int tid  = threadIdx.x;
    const int wid  = tid >> 6;       // 0..7; waves 0-3 mfma
    const int lane = tid & 63;
    const int dlt  = lane & 15;
    const int gma  = lane >> 4;

    {   // ---- W prep (once): 64 m-rows (m = kl*4+g) x 512 j, split ----
        const int m  = tid >> 3;
        const int j0 = (tid & 7) * 64;
        const int g = m & 3, kl = m >> 2;
        const float* wr = Whh + ((size_t)(dir*2048 + g*512 + kblk*16 + kl))*512 + j0;
#pragma unroll
        for (int seg = 0; seg < 4; ++seg) {
            unsigned hw[8], lw[8];
#pragma unroll
            for (int i = 0; i < 8; ++i) {
                unsigned q0 = pack_split(wr[seg*16 + 2*i]);
                unsigned q1 = pack_split(wr[seg*16 + 2*i + 1]);
                hw[i] = (q0 >> 16) | (q1 & 0xffff0000u);
                lw[i] = (q0 & 0xffffu) | (q1 << 16);
            }
            const int jb = (j0 + seg*16) * 2;
            const int of0 = (m << 10) + ((jb     ) ^ ((m & 7) << 4));
            const int of1 = (m << 10) + ((jb + 16) ^ ((m & 7) << 4));
            *(uint4*)(smem + LDS_W_HI + of0) = make_uint4(hw[0],hw[1],hw[2],hw[3]);
            *(uint4*)(smem + LDS_W_HI + of1) = make_uint4(hw[4],hw[5],hw[6],hw[7]);
            *(uint4*)(smem + LDS_W_LO + of0) = make_uint4(lw[0],lw[1],lw[2],lw[3]);
            *(uint4*)(smem + LDS_W_LO + of1) = make_uint4(lw[4],lw[5],lw[6],lw[7]);
        }
    }

    const int kg = kblk*16 + wid*4 + gma;   // this lane's k (mfma waves, wid<4)
    const int bb = b0 + dlt;                // this lane's b
    const int gbase = (((dir << 2) | bgrp) << 7);
    unsigned* mycnt = bar + gbase + (kblk & 3) * 32;

    float c = 0.f;
    if (first) {
        // h_{-1} = 0 in buffer NBUF-1: zero only this block's (16k x 16b) slice
        if (tid < 256) {
            int bl = tid >> 4, kl = tid & 15;
            astore_u32(hbig + ((size_t)(NBUF-1)*2 + dir)*32768
                            + (size_t)(b0 + bl)*512 + kblk*16 + kl, 0u);
        }
    } else if (wid < 4) {
        c = cbuf[(size_t)dir*32768 + (size_t)kg*64 + bb];
    }
    asm volatile("s_waitcnt vmcnt(0)" ::: "memory");
    __syncthreads();

    unsigned target = tgt0;

    for (int s = 0; s < tcount; ++s) {
        const int v = lo + s;
        const int t = dir ? (255 - v) : v;
        const int ridx = (v + NBUF - 1) & (NBUF-1);   // buffer holding h_{v-1}
        const int widx = v & (NBUF-1);                // buffer to publish h_v

        float p0, p1, p2, p3;
        if (wid < 4) {
            const size_t col = (size_t)s*64 + bb;
            p0 = pre[((size_t)(dir*2048 +        kg))*ncols + col];
            p1 = pre[((size_t)(dir*2048 +  512 + kg))*ncols + col];
            p2 = pre[((size_t)(dir*2048 + 1024 + kg))*ncols + col];
            p3 = pre[((size_t)(dir*2048 + 1536 + kg))*ncols + col];
        }

        // ---- group barrier: 4 distributed sub-counters (8 RMWs each) ----
        target += 8;
        if (tid == 0)
            __hip_atomic_fetch_add(mycnt, 1u, __ATOMIC_RELAXED, __HIP_MEMORY_SCOPE_AGENT);
        if (wid == 0) {
            while (true) {
                unsigned cnt = target;
                if (lane < 4)
                    cnt = __hip_atomic_load(bar + gbase + lane*32, __ATOMIC_RELAXED, __HIP_MEMORY_SCOPE_AGENT);
                if (__ballot(cnt >= target) == ~0ULL) break;
                __builtin_amdgcn_s_sleep(1);
            }
        }
        __syncthreads();                               // release block; LDS_B safe

        // ---- stage h_{v-1}[all k][b0..b0+16): PLAIN uint4 loads (L2-cached) ----
        const uint4* src4 = (const uint4*)(hbig + ((size_t)ridx*2 + dir)*32768);
#pragma unroll
        for (int i = 0; i < 4; ++i) {
            const int cc = i*512 + tid;
            const int bl = cc >> 7;
            const int jc = cc & 127;
            uint4 vv = src4[(size_t)(b0 + bl)*128 + jc];
            *(uint4*)(smem + LDS_B + jc*256 + ((bl ^ (jc & 7)) << 4)) = vv;
        }
        __syncthreads();

        // ---- mfma K-loop + epilogue (waves 0-3) ----
        if (wid < 4) {
            f32x4 acc = {p0, p1, p2, p3};
            const int arow = (wid*16 + dlt) << 10;
            const int axor = ((wid*16 + dlt) & 7) << 4;
            const int boff0 = (2*gma)*256   + ((dlt ^ (2*gma    )) << 4);
            const int boff1 = (2*gma+1)*256 + ((dlt ^ (2*gma + 1)) << 4);
#pragma unroll
            for (int kt = 0; kt < 16; ++kt) {
                const int jb  = (kt << 6) + (gma << 4);
                const int aof = arow + (jb ^ axor);
                short8 ah = *(const short8*)(smem + LDS_W_HI + aof);
                short8 al = *(const short8*)(smem + LDS_W_LO + aof);
                uint4 u0 = *(const uint4*)(smem + LDS_B + boff0 + (kt << 11));
                uint4 u1 = *(const uint4*)(smem + LDS_B + boff1 + (kt << 11));
                short8 bh, bl;
                unpack8(u0, u1, bh, bl);
                acc = __builtin_amdgcn_mfma_f32_16x16x32_bf16(ah, bh, acc, 0, 0, 0);
                acc = __builtin_amdgcn_mfma_f32_16x16x32_bf16(ah, bl, acc, 0, 0, 0);
                acc = __builtin_amdgcn_mfma_f32_16x16x32_bf16(al, bh, acc, 0, 0, 0);
            }
            float ig = fsig(acc[0]);
            float fg = fsig(acc[1]);
            float gg = ftanh(acc[2]);
            float og = fsig(acc[3]);
            c = fg * c + ig * gg;
            float h = og * ftanh(c);
            unsigned hpv = pack_split(h);
            // publish first, drain ONLY the publish, then issue out/cbuf stores
            astore_u32(hbig + ((size_t)widx*2 + dir)*32768 + (size_t)bb*512 + kg, hpv);
            asm volatile("s_waitcnt vmcnt(0)" ::: "memory");
            const size_t oidx = ((size_t)t*1024 + dir*512 + kg)*64 + bb;
            if (packout) ((unsigned*)outbuf)[oidx] = hpv;
            else         ((float*)outbuf)[oidx]    = h;
            if (s == tcount-1) cbuf[(size_t)dir*32768 + (size_t)kg*64 + bb] = c;
        }
        __syncthreads();   // all waves' publishes drained before tid0 re-arrives
    }
}

// ---------------- emissions (h1 f32) --------------------------------------------
__global__ __launch_bounds__(256) void emis_kernel(
    const float* __restrict__ h1, const float* __restrict__ Wout,
    const float* __restrict__ bout, float* __restrict__ em)
{
    const int s = blockIdx.x;
    const int tid = threadIdx.x;
    const int b = tid & 63;
    const int cl = tid >> 6;
    __shared__ float wl[32][128];
    float acc[8];
#pragma unroll
    for (int u = 0; u < 8; ++u) acc[u] = 0.f;
    const float* hp = h1 + (size_t)s * (1024*64);
    for (int f0 = 0; f0 < 1024; f0 += 128) {
        __syncthreads();
        for (int u = tid; u < 4096; u += 256) {
            int cc = u >> 7, ff = u & 127;
            wl[cc][ff] = Wout[(size_t)cc*1024 + f0 + ff];
        }
        __syncthreads();
        for (int ff = 0; ff < 128; ++ff) {
            float hv = hp[(size_t)(f0+ff)*64 + b];
#pragma unroll
            for (int u = 0; u < 8; ++u) acc[u] += hv * wl[cl + u*4][ff];
        }
    }
#pragma unroll
    for (int u = 0; u < 8; ++u) {
        int cc = cl + u*4;
        em[((size_t)b*T_ + s)*C_ + cc] = acc[u] + bout[cc];
    }
}

// ---------------- CRF Viterbi: half-wave split max + em prefetch ----------------
__global__ __launch_bounds__(64) void viterbi_kernel(
    const float* __restrict__ em, const float* __restrict__ start_t,
    const float* __restrict__ end_t, const float* __restrict__ trans,
    float* __restrict__ dout)
{
    const int b = blockIdx.x;
    const int l = threadIdx.x;
    const int j = l & 31;
    const int half = l >> 5;
    __shared__ float tr[C_*C_];
    __shared__ float sc[2][C_];
    __shared__ unsigned char hist[T_-1][C_];
    const float* emb = em + (size_t)b * T_ * C_;
    for (int i = l; i < C_*C_; i += 64) tr[i] = trans[i];
    if (l < C_) sc[0][l] = start_t[l] + emb[l];
    __syncthreads();

    float em_next = emb[C_ + j];
    for (int s = 1; s < T_; ++s) {
        const int cur = (s-1) & 1, nxt = s & 1;
        float em_cur = em_next;
        if (s + 1 < T_) em_next = emb[(size_t)(s+1)*C_ + j];
        float best = -3.4e38f; int bi = 0;
#pragma unroll
        for (int q = 0; q < 16; ++q) {
            const int i = half*16 + q;
            float v = sc[cur][i] + tr[i*C_ + j];
            if (v > best) { best = v; bi = i; }
        }
        float obest = __shfl_xor(best, 32);
        int   obi   = __shfl_xor(bi, 32);
        if (half == 0) { if (obest >  best) { best = obest; bi = obi; } }
        else           { if (obest >= best) { best = obest; bi = obi; } }
        if (half == 0) {
            sc[nxt][j] = best + em_cur;
            hist[s-1][j] = (unsigned char)bi;
        }
        __syncthreads();
    }
    if (l == 0) {
        const int cur = (T_-1) & 1;
        float best = -3.4e38f; int bi = 0;
        for (int i = 0; i < C_; ++i) {
            float v = sc[cur][i] + end_t[i];
            if (v > best) { best = v; bi = i; }
        }
        dout[(size_t)B_*T_ + b] = best;
        float* tout = dout + (size_t)b * T_;
        int tag = bi;
        tout[T_-1] = (float)tag;
        for (int s = T_-2; s >= 0; --s) {
            tag = hist[s][tag];
            tout[s] = (float)tag;
        }
    }
}

// ---------------- host launch ---------------------------------------------------
extern "C" void kernel_launch(void* const* d_in, const int* in_sizes, int n_in,
                              void* d_out, int out_size, void* d_ws, size_t ws_size,
                              hipStream_t stream) {
    const float* x    = (const float*)d_in[0];
    const float* Wih0 = (const float*)d_in[2];
    const float* Whh0 = (const float*)d_in[3];
    const float* b0   = (const float*)d_in[4];
    const float* Wih1 = (const float*)d_in[5];
    const float* Whh1 = (const float*)d_in[6];
    const float* b1   = (const float*)d_in[7];
    const float* Wout = (const float*)d_in[8];
    const float* bout = (const float*)d_in[9];
    const float* st   = (const float*)d_in[10];
    const float* en   = (const float*)d_in[11];
    const float* tr   = (const float*)d_in[12];
    float* dout = (float*)d_out;

    char* ws = (char*)d_ws;
    const size_t o_bar  = 0;                                   // 4 KiB
    const size_t o_cbuf = 4096;                                // 256 KiB
    const size_t o_hbig = o_cbuf + 262144;                     // 8 MiB (32 bufs)
    const size_t o_h0   = o_hbig + 8388608;                    // 64 MiB (packed u32)
    const size_t o_h1   = o_h0 + (size_t)67108864;             // 64 MiB (f32)
    const size_t o_pre  = o_h1 + (size_t)67108864;             // TCR MiB

    // ws-adaptive tiers: TC64+packW -> TC64 -> TC32+packW -> TC32 -> TC16
    int TCR; bool packW;
    const size_t base = o_pre;
    if      (ws_size >= base + 67108864ULL + 20971520ULL) { TCR = 64; packW = true;  }
    else if (ws_size >= base + 67108864ULL)               { TCR = 64; packW = false; }
    else if (ws_size >= base + 33554432ULL + 20971520ULL) { TCR = 32; packW = true;  }
    else if (ws_size >= base + 33554432ULL)               { TCR = 32; packW = false; }
    else                                                  { TCR = 16; packW = false; }
    const size_t presz = (size_t)4096 * TCR * 64 * 4;
    const size_t o_w0pk = o_pre + presz;
    const size_t o_w1pk = o_w0pk + 4194304;
    const int ncols = TCR * 64;
    const int nc = 256 / TCR;

    unsigned* bar  = (unsigned*)(ws + o_bar);
    float* cbuf    = (float*)(ws + o_cbuf);
    unsigned* hbig = (unsigned*)(ws + o_hbig);
    unsigned* h0pk = (unsigned*)(ws + o_h0);
    float* h1      = (float*)(ws + o_h1);
    float* pre     = (float*)(ws + o_pre);
    float* em      = (float*)(ws + o_pre);    // aliases pre (pre dead by emis time)
    unsigned* w0pk = packW ? (unsigned*)(ws + o_w0pk) : nullptr;
    unsigned* w1pk = packW ? (unsigned*)(ws + o_w1pk) : nullptr;

    hipMemsetAsync(bar, 0, 4096, stream);

    const int LDS_BYTES = 163840;
    hipFuncSetAttribute(reinterpret_cast<const void*>(lstm_scan),
                        hipFuncAttributeMaxDynamicSharedMemorySize, LDS_BYTES);

    if (packW) {
        pack_kernel<<<1024, 256, 0, stream>>>(Wih0, w0pk, 4096*256);
        pack_kernel<<<2048, 256, 0, stream>>>(Wih1, w1pk, 4096*1024);
    }

    dim3 gg(ncols/128, 32), bb(256);
    for (int ci = 0; ci < nc; ++ci) {
        int lo = ci * TCR;
        gemm_mfma<<<gg, bb, 0, stream>>>(w0pk, Wih0, x, b0, pre, F0_, 0, lo, ncols);
        lstm_scan<<<256, 512, LDS_BYTES, stream>>>(Whh0, pre, h0pk, 1, hbig, cbuf, bar,
                                                   lo, ci == 0 ? 1 : 0,
                                                   (unsigned)(lo * 8), TCR, ncols);
    }
    for (int ci = 0; ci < nc; ++ci) {
        int lo = ci * TCR;
        gemm_mfma<<<gg, bb, 0, stream>>>(w1pk, Wih1, h0pk, b1, pre, 1024, 1, lo, ncols);
        lstm_scan<<<256, 512, LDS_BYTES, stream>>>(Whh1, pre, h1, 0, hbig, cbuf, bar,
                                                   lo, ci == 0 ? 1 : 0,
                                                   (unsigned)((256 + lo) * 8), TCR, ncols);
    }
    emis_kernel<<<T_, bb, 0, stream>>>(h1, Wout, bout, em);
    viterbi_kernel<<<B_, 64, 0, stream>>>(em, st, en, tr, dout);
}

// Round 18
// 3090.219 us; speedup vs baseline: 1.3591x; 1.1459x over previous
//
#include <hip/hip_runtime.h>

#define B_   64
#define T_   256
#define H_   512
#define F0_  256
#define C_   32
#define NBUF 32

typedef short short8 __attribute__((ext_vector_type(8)));
typedef float f32x4 __attribute__((ext_vector_type(4)));
typedef unsigned long long u64;

__device__ __forceinline__ void astore_u32(unsigned* p, unsigned v) {
    __hip_atomic_store(p, v, __ATOMIC_RELAXED, __HIP_MEMORY_SCOPE_AGENT);
}

// fast activations: v_exp_f32 (2^x) + v_rcp_f32; rel err ~1e-6 (<< split-bf16 noise)
__device__ __forceinline__ float fsig(float x) {
    return __builtin_amdgcn_rcpf(1.f + __builtin_amdgcn_exp2f(-1.44269504f * x));
}
__device__ __forceinline__ float ftanh(float x) {
    return 1.f - 2.f * __builtin_amdgcn_rcpf(1.f + __builtin_amdgcn_exp2f(2.88539008f * x));
}

// split f32 -> (bf16 hi | bf16 lo) packed in u32 (hi in top 16, lo in bottom 16)
__device__ __forceinline__ unsigned pack_split(float x) {
    unsigned xb = __float_as_uint(x);
    unsigned hi = (xb + 0x7fffu + ((xb >> 16) & 1u)) & 0xffff0000u;
    float rest = x - __uint_as_float(hi);
    unsigned rb = __float_as_uint(rest);
    unsigned lo = (rb + 0x7fffu + ((rb >> 16) & 1u)) >> 16;
    return hi | (lo & 0xffffu);
}

// unpack 8 packed u32 (2x uint4) into hi-bf16x8 / lo-bf16x8 (r8-verified ordering)
__device__ __forceinline__ void unpack8(uint4 u0, uint4 u1, short8& hi, short8& lo) {
    union { uint4 u; short8 s; } H, L;
    H.u = make_uint4((u0.x >> 16) | (u0.y & 0xffff0000u),
                     (u0.z >> 16) | (u0.w & 0xffff0000u),
                     (u1.x >> 16) | (u1.y & 0xffff0000u),
                     (u1.z >> 16) | (u1.w & 0xffff0000u));
    L.u = make_uint4((u0.x & 0xffffu) | (u0.y << 16),
                     (u0.z & 0xffffu) | (u0.w << 16),
                     (u1.x & 0xffffu) | (u1.y << 16),
                     (u1.z & 0xffffu) | (u1.w << 16));
    hi = H.s; lo = L.s;
}

// ---------------- elementwise f32 -> packed split u32 ---------------------------
__global__ __launch_bounds__(256) void pack_kernel(
    const float* __restrict__ in, unsigned* __restrict__ out, int n)
{
    for (int i = blockIdx.x*256 + threadIdx.x; i < n; i += gridDim.x*256)
        out[i] = pack_split(in[i]);
}

// ---------------- MFMA split-bf16 GEMM: pre(4096, ncols) = W * B^T + bias ------
__global__ __launch_bounds__(256) void gemm_mfma(
    const unsigned* __restrict__ Wpk, const float* __restrict__ Wf,
    const void* __restrict__ Bsrc, const float* __restrict__ bias,
    float* __restrict__ Cout, int K, int mode, int lo, int ncols)
{
    __shared__ __align__(16) unsigned As[4096];
    __shared__ __align__(16) unsigned Bs[4096];
    char* asb = (char*)As; char* bsb = (char*)Bs;
    const int m0 = blockIdx.y * 128;
    const int n0 = blockIdx.x * 128;
    const int dir = m0 >> 11;
    const int tid = threadIdx.x;
    const int w = tid >> 6;
    const int lane = tid & 63;
    const int dlt = lane & 15, gma = lane >> 4;
    const int mw = (w >> 1) * 64, nw = (w & 1) * 64;
    const int srow = tid >> 1;
    const int sh   = tid & 1;

    f32x4 acc[4][4];
#pragma unroll
    for (int mi = 0; mi < 4; ++mi)
#pragma unroll
        for (int ni = 0; ni < 4; ++ni) acc[mi][ni] = (f32x4){0.f,0.f,0.f,0.f};

    for (int k0 = 0; k0 < K; k0 += 32) {
        __syncthreads();
        {   // A tile
            unsigned v[16];
            if (Wpk) {
                const unsigned* ap = Wpk + (size_t)(m0 + srow)*K + k0 + sh*16;
                uint4 q0 = *(const uint4*)(ap);
                uint4 q1 = *(const uint4*)(ap + 4);
                uint4 q2 = *(const uint4*)(ap + 8);
                uint4 q3 = *(const uint4*)(ap + 12);
                v[0]=q0.x; v[1]=q0.y; v[2]=q0.z; v[3]=q0.w;
                v[4]=q1.x; v[5]=q1.y; v[6]=q1.z; v[7]=q1.w;
                v[8]=q2.x; v[9]=q2.y; v[10]=q2.z; v[11]=q2.w;
                v[12]=q3.x; v[13]=q3.y; v[14]=q3.z; v[15]=q3.w;
            } else {
                const float* ap = Wf + (size_t)(m0 + srow)*K + k0 + sh*16;
#pragma unroll
                for (int i = 0; i < 16; ++i) v[i] = pack_split(ap[i]);
            }
#pragma unroll
            for (int j = 0; j < 4; ++j) {
                int c = sh*4 + j;
                int byte = srow*128 + ((c ^ (srow & 7)) << 4);
                *(uint4*)(asb + byte) = make_uint4(v[4*j],v[4*j+1],v[4*j+2],v[4*j+3]);
            }
        }
        {   // B tile
            const int n = n0 + srow;
            const int bb2 = n & 63, tloc = n >> 6;
            const int t = dir ? (255 - lo - tloc) : (lo + tloc);
            unsigned v[16];
            if (mode == 0) {
                const float* bp = (const float*)Bsrc + ((size_t)bb2*T_ + t)*F0_ + k0 + sh*16;
#pragma unroll
                for (int i = 0; i < 16; ++i) v[i] = pack_split(bp[i]);
            } else {
                const unsigned* bp = (const unsigned*)Bsrc
                    + (size_t)t*(1024*64) + (size_t)(k0 + sh*16)*64 + bb2;
#pragma unroll
                for (int i = 0; i < 16; ++i) v[i] = bp[(size_t)i*64];
            }
#pragma unroll
            for (int j = 0; j < 4; ++j) {
                int c = sh*4 + j;
                int byte = srow*128 + ((c ^ (srow & 7)) << 4);
                *(uint4*)(bsb + byte) = make_uint4(v[4*j],v[4*j+1],v[4*j+2],v[4*j+3]);
            }
        }
        __syncthreads();

        short8 ah[4], al[4];
#pragma unroll
        for (int mi = 0; mi < 4; ++mi) {
            int base = (mw + mi*16 + dlt) * 128;
            uint4 u0 = *(const uint4*)(asb + base + (((gma*2    ) ^ (dlt & 7)) << 4));
            uint4 u1 = *(const uint4*)(asb + base + (((gma*2 + 1) ^ (dlt & 7)) << 4));
            unpack8(u0, u1, ah[mi], al[mi]);
        }
#pragma unroll
        for (int ni = 0; ni < 4; ++ni) {
            int base = (nw + ni*16 + dlt) * 128;
            uint4 u0 = *(const uint4*)(bsb + base + (((gma*2    ) ^ (dlt & 7)) << 4));
            uint4 u1 = *(const uint4*)(bsb + base + (((gma*2 + 1) ^ (dlt & 7)) << 4));
            short8 bh, bl;
            unpack8(u0, u1, bh, bl);
#pragma unroll
            for (int mi = 0; mi < 4; ++mi) {
                acc[mi][ni] = __builtin_amdgcn_mfma_f32_16x16x32_bf16(ah[mi], bh, acc[mi][ni], 0, 0, 0);
                acc[mi][ni] = __builtin_amdgcn_mfma_f32_16x16x32_bf16(ah[mi], bl, acc[mi][ni], 0, 0, 0);
                acc[mi][ni] = __builtin_amdgcn_mfma_f32_16x16x32_bf16(al[mi], bh, acc[mi][ni], 0, 0, 0);
            }
        }
    }

#pragma unroll
    for (int mi = 0; mi < 4; ++mi)
#pragma unroll
        for (int ni = 0; ni < 4; ++ni) {
            const int n = n0 + nw + ni*16 + dlt;
#pragma unroll
            for (int r = 0; r < 4; ++r) {
                const int m = m0 + mw + mi*16 + gma*4 + r;
                Cout[(size_t)m*ncols + n] = acc[mi][ni][r] + bias[m];
            }
        }
}

// ---------------- persistent bidirectional LSTM scan, MFMA split-bf16 ----------
// r14 structure VERBATIM (512 threads, 2 dir x 32 kblk x 4 bgrp, LDS B-staging,
// rotating 32 h-buffers, single group counter barrier, sleep(2), out-store after
// publish drain, fast activations). Only addition: scol0 (pre column window base)
// so the GEMM can produce larger chunks than the scan consumes.
#define LDS_W_HI 0
#define LDS_W_LO 65536
#define LDS_B    131072

__global__ __launch_bounds__(512, 1) void lstm_scan(
    const float* __restrict__ Whh,   // (2, 2048, 512)
    const float* __restrict__ pre,   // (4096, ncols)
    void* __restrict__ outbuf,       // (T_, 1024, B_) f32 or packed u32
    int packout,
    unsigned* __restrict__ hbig,     // [NBUF][2 dir][64 b][512 k] packed u32
    float* __restrict__ cbuf,        // [2 dir][512 k][64 b]
    unsigned* __restrict__ bar,      // [8 group] counters, 128B apart
    int lo, int first, unsigned tgt0, int tcount, int ncols, int scol0)
{
    extern __shared__ char smem[];
    const int bid  = blockIdx.x;
    const int dir  = bid >> 7;
    const int r7   = bid & 127;
    const int kblk = r7 >> 2;        // 0..31
    const int bgrp = r7 & 3;         // 0..3
    const int b0   = bgrp * 16;
    const int tid  = threadIdx.x;
    const int wid  = tid >> 6;       // 0..7; waves 0-3 mfma
    const int lane = tid & 63;
    const int dlt  = lane & 15;
    const int gma  = lane >> 4;

    {   // ---- W prep (once): 64 m-rows (m = kl*4+g) x 512 j, split ----
        const int m  = tid >> 3;
        const int j0 = (tid & 7) * 64;
        const int g = m & 3, kl = m >> 2;
        const float* wr = Whh + ((size_t)(dir*2048 + g*512 + kblk*16 + kl))*512 + j0;
#pragma unroll
        for (int seg = 0; seg < 4; ++seg) {
            unsigned hw[8], lw[8];
#pragma unroll
            for (int i = 0; i < 8; ++i) {
                unsigned q0 = pack_split(wr[seg*16 + 2*i]);
                unsigned q1 = pack_split(wr[seg*16 + 2*i + 1]);
                hw[i] = (q0 >> 16) | (q1 & 0xffff0000u);
                lw[i] = (q0 & 0xffffu) | (q1 << 16);
            }
            const int jb = (j0 + seg*16) * 2;
            const int of0 = (m << 10) + ((jb     ) ^ ((m & 7) << 4));
            const int of1 = (m << 10) + ((jb + 16) ^ ((m & 7) << 4));
            *(uint4*)(smem + LDS_W_HI + of0) = make_uint4(hw[0],hw[1],hw[2],hw[3]);
            *(uint4*)(smem + LDS_W_HI + of1) = make_uint4(hw[4],hw[5],hw[6],hw[7]);
            *(uint4*)(smem + LDS_W_LO + of0) = make_uint4(lw[0],lw[1],lw[2],lw[3]);
            *(uint4*)(smem + LDS_W_LO + of1) = make_uint4(lw[4],lw[5],lw[6],lw[7]);
        }
    }

    const int kg = kblk*16 + wid*4 + gma;   // this lane's k (mfma waves, wid<4)
    const int bb = b0 + dlt;                // this lane's b
    unsigned* mycnt = bar + (((dir << 2) | bgrp) * 32);

    float c = 0.f;
    if (first) {
        // h_{-1} = 0 in buffer NBUF-1: zero only this block's (16k x 16b) slice
        if (tid < 256) {
            int bl = tid >> 4, kl = tid & 15;
            astore_u32(hbig + ((size_t)(NBUF-1)*2 + dir)*32768
                            + (size_t)(b0 + bl)*512 + kblk*16 + kl, 0u);
        }
    } else if (wid < 4) {
        c = cbuf[(size_t)dir*32768 + (size_t)kg*64 + bb];
    }
    asm volatile("s_waitcnt vmcnt(0)" ::: "memory");
    __syncthreads();

    unsigned target = tgt0;

    for (int s = 0; s < tcount; ++s) {
        const int v = lo + s;
        const int t = dir ? (255 - v) : v;
        const int ridx = (v + NBUF - 1) & (NBUF-1);   // buffer holding h_{v-1}
        const int widx = v & (NBUF-1);                // buffer to publish h_v

        float p0, p1, p2, p3;
        if (wid < 4) {
            const size_t col = (size_t)(scol0 + s*64) + bb;
            p0 = pre[((size_t)(dir*2048 +        kg))*ncols + col];
            p1 = pre[((size_t)(dir*2048 +  512 + kg))*ncols + col];
            p2 = pre[((size_t)(dir*2048 + 1024 + kg))*ncols + col];
            p3 = pre[((size_t)(dir*2048 + 1536 + kg))*ncols + col];
        }

        // ---- group barrier (32 blocks, single counter, relaxed) ----
        target += 32;
        if (tid == 0) {
            __hip_atomic_fetch_add(mycnt, 1u, __ATOMIC_RELAXED, __HIP_MEMORY_SCOPE_AGENT);
            while (__hip_atomic_load(mycnt, __ATOMIC_RELAXED, __HIP_MEMORY_SCOPE_AGENT) < target)
                __builtin_amdgcn_s_sleep(2);
        }
        __syncthreads();

        // ---- stage h_{v-1}[all k][b0..b0+16): PLAIN uint4 loads (L2-cached) ----
        const uint4* src4 = (const uint4*)(hbig + ((size_t)ridx*2 + dir)*32768);
#pragma unroll
        for (int i = 0; i < 4; ++i) {
            const int cc = i*512 + tid;
            const int bl = cc >> 7;
            const int jc = cc & 127;
            uint4 vv = src4[(size_t)(b0 + bl)*128 + jc];
            *(uint4*)(smem + LDS_B + jc*256 + ((bl ^ (jc & 7)) << 4)) = vv;
        }
        __syncthreads();

        // ---- mfma K-loop + epilogue (waves 0-3) ----
        if (wid < 4) {
            f32x4 acc = {p0, p1, p2, p3};
            const int arow = (wid*16 + dlt) << 10;
            const int axor = ((wid*16 + dlt) & 7) << 4;
            const int boff0 = (2*gma)*256   + ((dlt ^ (2*gma    )) << 4);
            const int boff1 = (2*gma+1)*256 + ((dlt ^ (2*gma + 1)) << 4);
#pragma unroll
            for (int kt = 0; kt < 16; ++kt) {
                const int jb  = (kt << 6) + (gma << 4);
                const int aof = arow + (jb ^ axor);
                short8 ah = *(const short8*)(smem + LDS_W_HI + aof);
                short8 al = *(const short8*)(smem + LDS_W_LO + aof);
                uint4 u0 = *(const uint4*)(smem + LDS_B + boff0 + (kt << 11));
                uint4 u1 = *(const uint4*)(smem + LDS_B + boff1 + (kt << 11));
                short8 bh, bl;
                unpack8(u0, u1, bh, bl);
                acc = __builtin_amdgcn_mfma_f32_16x16x32_bf16(ah, bh, acc, 0, 0, 0);
                acc = __builtin_amdgcn_mfma_f32_16x16x32_bf16(ah, bl, acc, 0, 0, 0);
                acc = __builtin_amdgcn_mfma_f32_16x16x32_bf16(al, bh, acc, 0, 0, 0);
            }
            float ig = fsig(acc[0]);
            float fg = fsig(acc[1]);
            float gg = ftanh(acc[2]);
            float og = fsig(acc[3]);
            c = fg * c + ig * gg;
            float h = og * ftanh(c);
            unsigned hpv = pack_split(h);
            // publish first, drain ONLY the publish, then issue out/cbuf stores
            astore_u32(hbig + ((size_t)widx*2 + dir)*32768 + (size_t)bb*512 + kg, hpv);
            asm volatile("s_waitcnt vmcnt(0)" ::: "memory");
            const size_t oidx = ((size_t)t*1024 + dir*512 + kg)*64 + bb;
            if (packout) ((unsigned*)outbuf)[oidx] = hpv;
            else         ((float*)outbuf)[oidx]    = h;
            if (s == tcount-1) cbuf[(size_t)dir*32768 + (size_t)kg*64 + bb] = c;
        }
        __syncthreads();   // all waves' publishes drained before tid0 re-arrives
    }
}

// ---------------- emissions (h1 f32) --------------------------------------------
__global__ __launch_bounds__(256) void emis_kernel(
    const float* __restrict__ h1, const float* __restrict__ Wout,
    const float* __restrict__ bout, float* __restrict__ em)
{
    const int s = blockIdx.x;
    const int tid = threadIdx.x;
    const int b = tid & 63;
    const int cl = tid >> 6;
    __shared__ float wl[32][128];
    float acc[8];
#pragma unroll
    for (int u = 0; u < 8; ++u) acc[u] = 0.f;
    const float* hp = h1 + (size_t)s * (1024*64);
    for (int f0 = 0; f0 < 1024; f0 += 128) {
        __syncthreads();
        for (int u = tid; u < 4096; u += 256) {
            int cc = u >> 7, ff = u & 127;
            wl[cc][ff] = Wout[(size_t)cc*1024 + f0 + ff];
        }
        __syncthreads();
        for (int ff = 0; ff < 128; ++ff) {
            float hv = hp[(size_t)(f0+ff)*64 + b];
#pragma unroll
            for (int u = 0; u < 8; ++u) acc[u] += hv * wl[cl + u*4][ff];
        }
    }
#pragma unroll
    for (int u = 0; u < 8; ++u) {
        int cc = cl + u*4;
        em[((size_t)b*T_ + s)*C_ + cc] = acc[u] + bout[cc];
    }
}

// ---------------- CRF Viterbi: scores in registers, shfl broadcasts, 0 syncs ----
__global__ __launch_bounds__(64) void viterbi_kernel(
    const float* __restrict__ em, const float* __restrict__ start_t,
    const float* __restrict__ end_t, const float* __restrict__ trans,
    float* __restrict__ dout)
{
    const int b = blockIdx.x;
    const int l = threadIdx.x;
    const int j = l & 31;
    const int half = l >> 5;
    __shared__ float tr[C_*C_];
    __shared__ float scl[C_];
    __shared__ unsigned char hist[T_-1][C_];
    const float* emb = em + (size_t)b * T_ * C_;
    for (int i = l; i < C_*C_; i += 64) tr[i] = trans[i];
    float myscore = start_t[j] + emb[j];        // lane j and j+32 both hold score[j]
    float em_next = emb[C_ + j];
    __syncthreads();

    for (int s = 1; s < T_; ++s) {
        float em_cur = em_next;
        if (s + 1 < T_) em_next = emb[(size_t)(s+1)*C_ + j];
        float best = -3.4e38f; int bi = 0;
#pragma unroll
        for (int q = 0; q < 16; ++q) {
            const int i = half*16 + q;
            float sv = __shfl(myscore, i);      // lane i holds score[i]
            float v = sv + tr[i*C_ + j];
            if (v > best) { best = v; bi = i; }
        }
        float obest = __shfl_xor(best, 32);
        int   obi   = __shfl_xor(bi, 32);
        // first-max semantics: lower-i half wins ties
        if (half == 0) { if (obest >  best) { best = obest; bi = obi; } }
        else           { if (obest >= best) { best = obest; bi = obi; } }
        float ns = best + em_cur;               // identical value in both halves
        myscore = __shfl(ns, j);                // rebroadcast from half-0 lane j
        if (half == 0) hist[s-1][j] = (unsigned char)bi;
    }
    if (half == 0) scl[j] = myscore;
    __syncthreads();
    if (l == 0) {
        float best = -3.4e38f; int bi = 0;
        for (int i = 0; i < C_; ++i) {
            float v = scl[i] + end_t[i];
            if (v > best) { best = v; bi = i; }
        }
        dout[(size_t)B_*T_ + b] = best;
        float* tout = dout + (size_t)b * T_;
        int tag = bi;
        tout[T_-1] = (float)tag;
        for (int s = T_-2; s >= 0; --s) {
            tag = hist[s][tag];
            tout[s] = (float)tag;
        }
    }
}

// ---------------- host launch ---------------------------------------------------
extern "C" void kernel_launch(void* const* d_in, const int* in_sizes, int n_in,
                              void* d_out, int out_size, void* d_ws, size_t ws_size,
                              hipStream_t stream) {
    const float* x    = (const float*)d_in[0];
    const float* Wih0 = (const float*)d_in[2];
    const float* Whh0 = (const float*)d_in[3];
    const float* b0   = (const float*)d_in[4];
    const float* Wih1 = (const float*)d_in[5];
    const float* Whh1 = (const float*)d_in[6];
    const float* b1   = (const float*)d_in[7];
    const float* Wout = (const float*)d_in[8];
    const float* bout = (const float*)d_in[9];
    const float* st   = (const float*)d_in[10];
    const float* en   = (const float*)d_in[11];
    const float* tr   = (const float*)d_in[12];
    float* dout = (float*)d_out;

    char* ws = (char*)d_ws;
    const size_t o_bar  = 0;                                   // 4 KiB
    const size_t o_cbuf = 4096;                                // 256 KiB
    const size_t o_hbig = o_cbuf + 262144;                     // 8 MiB (32 bufs)
    const size_t o_h0   = o_hbig + 8388608;                    // 64 MiB (packed u32)
    const size_t o_h1   = o_h0 + (size_t)67108864;             // 64 MiB (f32)
    const size_t o_pre  = o_h1 + (size_t)67108864;             // GC MiB

    // tiers: GC = gemm chunk (t-steps per gemm dispatch), SC = scan chunk
    int GC; bool packW;
    const size_t base = o_pre;
    if      (ws_size >= base + 67108864ULL + 20971520ULL) { GC = 64; packW = true;  }
    else if (ws_size >= base + 33554432ULL + 20971520ULL) { GC = 32; packW = true;  }
    else if (ws_size >= base + 33554432ULL)               { GC = 32; packW = false; }
    else                                                  { GC = 16; packW = false; }
    const int SC = (GC < 32) ? 16 : 32;
    const size_t presz = (size_t)4096 * GC * 64 * 4;
    const size_t o_w0pk = o_pre + presz;
    const size_t o_w1pk = o_w0pk + 4194304;
    const int ncols = GC * 64;

    unsigned* bar  = (unsigned*)(ws + o_bar);
    float* cbuf    = (float*)(ws + o_cbuf);
    unsigned* hbig = (unsigned*)(ws + o_hbig);
    unsigned* h0pk = (unsigned*)(ws + o_h0);
    float* h1      = (float*)(ws + o_h1);
    float* pre     = (float*)(ws + o_pre);
    float* em      = (float*)(ws + o_pre);    // aliases pre (pre dead by emis time)
    unsigned* w0pk = packW ? (unsigned*)(ws + o_w0pk) : nullptr;
    unsigned* w1pk = packW ? (unsigned*)(ws + o_w1pk) : nullptr;

    hipMemsetAsync(bar, 0, 4096, stream);

    const int LDS_BYTES = 163840;
    hipFuncSetAttribute(reinterpret_cast<const void*>(lstm_scan),
                        hipFuncAttributeMaxDynamicSharedMemorySize, LDS_BYTES);

    if (packW) {
        pack_kernel<<<1024, 256, 0, stream>>>(Wih0, w0pk, 4096*256);
        pack_kernel<<<2048, 256, 0, stream>>>(Wih1, w1pk, 4096*1024);
    }

    dim3 gg(ncols/128, 32), bb(256);
    for (int glo = 0; glo < 256; glo += GC) {
        gemm_mfma<<<gg, bb, 0, stream>>>(w0pk, Wih0, x, b0, pre, F0_, 0, glo, ncols);
        for (int slo = glo; slo < glo + GC; slo += SC)
            lstm_scan<<<256, 512, LDS_BYTES, stream>>>(
                Whh0, pre, h0pk, 1, hbig, cbuf, bar,
                slo, slo == 0 ? 1 : 0, (unsigned)(slo * 32), SC, ncols, (slo - glo) * 64);
    }
    for (int glo = 0; glo < 256; glo += GC) {
        gemm_mfma<<<gg, bb, 0, stream>>>(w1pk, Wih1, h0pk, b1, pre, 1024, 1, glo, ncols);
        for (int slo = glo; slo < glo + GC; slo += SC)
            lstm_scan<<<256, 512, LDS_BYTES, stream>>>(
                Whh1, pre, h1, 0, hbig, cbuf, bar,
                slo, slo == 0 ? 1 : 0, (unsigned)((256 + slo) * 32), SC, ncols, (slo - glo) * 64);
    }
    emis_kernel<<<T_, bb, 0, stream>>>(h1, Wout, bout, em);
    viterbi_kernel<<<B_, 64, 0, stream>>>(em, st, en, tr, dout);
}

// Round 19
// 2983.278 us; speedup vs baseline: 1.4078x; 1.0358x over previous
//
#include <hip/hip_runtime.h>

#define B_   64
#define T_   256
#define H_   512
#define F0_  256
#define C_   32

typedef short short8 __attribute__((ext_vector_type(8)));
typedef float f32x4 __attribute__((ext_vector_type(4)));
typedef unsigned long long u64;

__device__ __forceinline__ void astore_u32(unsigned* p, unsigned v) {
    __hip_atomic_store(p, v, __ATOMIC_RELAXED, __HIP_MEMORY_SCOPE_AGENT);
}

// fast activations: v_exp_f32 (2^x) + v_rcp_f32; rel err ~1e-6 (<< split-bf16 noise)
__device__ __forceinline__ float fsig(float x) {
    return __builtin_amdgcn_rcpf(1.f + __builtin_amdgcn_exp2f(-1.44269504f * x));
}
__device__ __forceinline__ float ftanh(float x) {
    return 1.f - 2.f * __builtin_amdgcn_rcpf(1.f + __builtin_amdgcn_exp2f(2.88539008f * x));
}

// split f32 -> (bf16 hi | bf16 lo) packed in u32 (hi in top 16, lo in bottom 16)
__device__ __forceinline__ unsigned pack_split(float x) {
    unsigned xb = __float_as_uint(x);
    unsigned hi = (xb + 0x7fffu + ((xb >> 16) & 1u)) & 0xffff0000u;
    float rest = x - __uint_as_float(hi);
    unsigned rb = __float_as_uint(rest);
    unsigned lo = (rb + 0x7fffu + ((rb >> 16) & 1u)) >> 16;
    return hi | (lo & 0xffffu);
}

// unpack 8 packed u32 (2x uint4) into hi-bf16x8 / lo-bf16x8 (r8-verified ordering)
__device__ __forceinline__ void unpack8(uint4 u0, uint4 u1, short8& hi, short8& lo) {
    union { uint4 u; short8 s; } H, L;
    H.u = make_uint4((u0.x >> 16) | (u0.y & 0xffff0000u),
                     (u0.z >> 16) | (u0.w & 0xffff0000u),
                     (u1.x >> 16) | (u1.y & 0xffff0000u),
                     (u1.z >> 16) | (u1.w & 0xffff0000u));
    L.u = make_uint4((u0.x & 0xffffu) | (u0.y << 16),
                     (u0.z & 0xffffu) | (u0.w << 16),
                     (u1.x & 0xffffu) | (u1.y << 16),
                     (u1.z & 0xffffu) | (u1.w << 16));
    hi = H.s; lo = L.s;
}

// ---------------- elementwise f32 -> packed split u32 ---------------------------
__global__ __launch_bounds__(256) void pack_kernel(
    const float* __restrict__ in, unsigned* __restrict__ out, int n)
{
    for (int i = blockIdx.x*256 + threadIdx.x; i < n; i += gridDim.x*256)
        out[i] = pack_split(in[i]);
}

// ---------------- MFMA split-bf16 GEMM: pre(4096, ncols) = W * B^T + bias ------
__global__ __launch_bounds__(256) void gemm_mfma(
    const unsigned* __restrict__ Wpk, const float* __restrict__ Wf,
    const void* __restrict__ Bsrc, const float* __restrict__ bias,
    float* __restrict__ Cout, int K, int mode, int lo, int ncols)
{
    __shared__ __align__(16) unsigned As[4096];
    __shared__ __align__(16) unsigned Bs[4096];
    char* asb = (char*)As; char* bsb = (char*)Bs;
    const int m0 = blockIdx.y * 128;
    const int n0 = blockIdx.x * 128;
    const int dir = m0 >> 11;
    const int tid = threadIdx.x;
    const int w = tid >> 6;
    const int lane = tid & 63;
    const int dlt = lane & 15, gma = lane >> 4;
    const int mw = (w >> 1) * 64, nw = (w & 1) * 64;
    const int srow = tid >> 1;
    const int sh   = tid & 1;

    f32x4 acc[4][4];
#pragma unroll
    for (int mi = 0; mi < 4; ++mi)
#pragma unroll
        for (int ni = 0; ni < 4; ++ni) acc[mi][ni] = (f32x4){0.f,0.f,0.f,0.f};

    for (int k0 = 0; k0 < K; k0 += 32) {
        __syncthreads();
        {   // A tile
            unsigned v[16];
            if (Wpk) {
                const unsigned* ap = Wpk + (size_t)(m0 + srow)*K + k0 + sh*16;
                uint4 q0 = *(const uint4*)(ap);
                uint4 q1 = *(const uint4*)(ap + 4);
                uint4 q2 = *(const uint4*)(ap + 8);
                uint4 q3 = *(const uint4*)(ap + 12);
                v[0]=q0.x; v[1]=q0.y; v[2]=q0.z; v[3]=q0.w;
                v[4]=q1.x; v[5]=q1.y; v[6]=q1.z; v[7]=q1.w;
                v[8]=q2.x; v[9]=q2.y; v[10]=q2.z; v[11]=q2.w;
                v[12]=q3.x; v[13]=q3.y; v[14]=q3.z; v[15]=q3.w;
            } else {
                const float* ap = Wf + (size_t)(m0 + srow)*K + k0 + sh*16;
#pragma unroll
                for (int i = 0; i < 16; ++i) v[i] = pack_split(ap[i]);
            }
#pragma unroll
            for (int j = 0; j < 4; ++j) {
                int c = sh*4 + j;
                int byte = srow*128 + ((c ^ (srow & 7)) << 4);
                *(uint4*)(asb + byte) = make_uint4(v[4*j],v[4*j+1],v[4*j+2],v[4*j+3]);
            }
        }
        {   // B tile
            const int n = n0 + srow;
            const int bb2 = n & 63, tloc = n >> 6;
            const int t = dir ? (255 - lo - tloc) : (lo + tloc);
            unsigned v[16];
            if (mode == 0) {
                const float* bp = (const float*)Bsrc + ((size_t)bb2*T_ + t)*F0_ + k0 + sh*16;
#pragma unroll
                for (int i = 0; i < 16; ++i) v[i] = pack_split(bp[i]);
            } else {
                const unsigned* bp = (const unsigned*)Bsrc
                    + (size_t)t*(1024*64) + (size_t)(k0 + sh*16)*64 + bb2;
#pragma unroll
                for (int i = 0; i < 16; ++i) v[i] = bp[(size_t)i*64];
            }
#pragma unroll
            for (int j = 0; j < 4; ++j) {
                int c = sh*4 + j;
                int byte = srow*128 + ((c ^ (srow & 7)) << 4);
                *(uint4*)(bsb + byte) = make_uint4(v[4*j],v[4*j+1],v[4*j+2],v[4*j+3]);
            }
        }
        __syncthreads();

        short8 ah[4], al[4];
#pragma unroll
        for (int mi = 0; mi < 4; ++mi) {
            int base = (mw + mi*16 + dlt) * 128;
            uint4 u0 = *(const uint4*)(asb + base + (((gma*2    ) ^ (dlt & 7)) << 4));
            uint4 u1 = *(const uint4*)(asb + base + (((gma*2 + 1) ^ (dlt & 7)) << 4));
            unpack8(u0, u1, ah[mi], al[mi]);
        }
#pragma unroll
        for (int ni = 0; ni < 4; ++ni) {
            int base = (nw + ni*16 + dlt) * 128;
            uint4 u0 = *(const uint4*)(bsb + base + (((gma*2    ) ^ (dlt & 7)) << 4));
            uint4 u1 = *(const uint4*)(bsb + base + (((gma*2 + 1) ^ (dlt & 7)) << 4));
            short8 bh, bl;
            unpack8(u0, u1, bh, bl);
#pragma unroll
            for (int mi = 0; mi < 4; ++mi) {
                acc[mi][ni] = __builtin_amdgcn_mfma_f32_16x16x32_bf16(ah[mi], bh, acc[mi][ni], 0, 0, 0);
                acc[mi][ni] = __builtin_amdgcn_mfma_f32_16x16x32_bf16(ah[mi], bl, acc[mi][ni], 0, 0, 0);
                acc[mi][ni] = __builtin_amdgcn_mfma_f32_16x16x32_bf16(al[mi], bh, acc[mi][ni], 0, 0, 0);
            }
        }
    }

#pragma unroll
    for (int mi = 0; mi < 4; ++mi)
#pragma unroll
        for (int ni = 0; ni < 4; ++ni) {
            const int n = n0 + nw + ni*16 + dlt;
#pragma unroll
            for (int r = 0; r < 4; ++r) {
                const int m = m0 + mw + mi*16 + gma*4 + r;
                Cout[(size_t)m*ncols + n] = acc[mi][ni][r] + bias[m];
            }
        }
}

// ---------------- persistent bidirectional LSTM scan, MFMA split-bf16 ----------
// r14 structure VERBATIM (512 threads, 2 dir x 32 kblk x 4 bgrp, LDS B-staging,
// single group counter barrier + sleep(2), out-store after publish drain, fast
// activations). Parameterized: scol0 (pre column window base) and nbm (rotating
// buffer count mask; NBUF = nbm+1 >= tcount keeps write-once-read-once/launch).
#define LDS_W_HI 0
#define LDS_W_LO 65536
#define LDS_B    131072

__global__ __launch_bounds__(512, 1) void lstm_scan(
    const float* __restrict__ Whh,   // (2, 2048, 512)
    const float* __restrict__ pre,   // (4096, ncols)
    void* __restrict__ outbuf,       // (T_, 1024, B_) f32 or packed u32
    int packout,
    unsigned* __restrict__ hbig,     // [nbm+1][2 dir][64 b][512 k] packed u32
    float* __restrict__ cbuf,        // [2 dir][512 k][64 b]
    unsigned* __restrict__ bar,      // [8 group] counters, 128B apart
    int lo, int first, unsigned tgt0, int tcount, int ncols, int scol0, int nbm)
{
    extern __shared__ char smem[];
    const int bid  = blockIdx.x;
    const int dir  = bid >> 7;
    const int r7   = bid & 127;
    const int kblk = r7 >> 2;        // 0..31
    const int bgrp = r7 & 3;         // 0..3
    const int b0   = bgrp * 16;
    const int tid  = threadIdx.x;
    const int wid  = tid >> 6;       // 0..7; waves 0-3 mfma
    const int lane = tid & 63;
    const int dlt  = lane & 15;
    const int gma  = lane >> 4;

    {   // ---- W prep (once): 64 m-rows (m = kl*4+g) x 512 j, split ----
        const int m  = tid >> 3;
        const int j0 = (tid & 7) * 64;
        const int g = m & 3, kl = m >> 2;
        const float* wr = Whh + ((size_t)(dir*2048 + g*512 + kblk*16 + kl))*512 + j0;
#pragma unroll
        for (int seg = 0; seg < 4; ++seg) {
            unsigned hw[8], lw[8];
#pragma unroll
            for (int i = 0; i < 8; ++i) {
                unsigned q0 = pack_split(wr[seg*16 + 2*i]);
                unsigned q1 = pack_split(wr[seg*16 + 2*i + 1]);
                hw[i] = (q0 >> 16) | (q1 & 0xffff0000u);
                lw[i] = (q0 & 0xffffu) | (q1 << 16);
            }
            const int jb = (j0 + seg*16) * 2;
            const int of0 = (m << 10) + ((jb     ) ^ ((m & 7) << 4));
            const int of1 = (m << 10) + ((jb + 16) ^ ((m & 7) << 4));
            *(uint4*)(smem + LDS_W_HI + of0) = make_uint4(hw[0],hw[1],hw[2],hw[3]);
            *(uint4*)(smem + LDS_W_HI + of1) = make_uint4(hw[4],hw[5],hw[6],hw[7]);
            *(uint4*)(smem + LDS_W_LO + of0) = make_uint4(lw[0],lw[1],lw[2],lw[3]);
            *(uint4*)(smem + LDS_W_LO + of1) = make_uint4(lw[4],lw[5],lw[6],lw[7]);
        }
    }

    const int kg = kblk*16 + wid*4 + gma;   // this lane's k (mfma waves, wid<4)
    const int bb = b0 + dlt;                // this lane's b
    unsigned* mycnt = bar + (((dir << 2) | bgrp) * 32);

    float c = 0.f;
    if (first) {
        // h_{-1} = 0 in buffer nbm: zero only this block's (16k x 16b) slice
        if (tid < 256) {
            int bl = tid >> 4, kl = tid & 15;
            astore_u32(hbig + ((size_t)nbm*2 + dir)*32768
                            + (size_t)(b0 + bl)*512 + kblk*16 + kl, 0u);
        }
    } else if (wid < 4) {
        c = cbuf[(size_t)dir*32768 + (size_t)kg*64 + bb];
    }
    asm volatile("s_waitcnt vmcnt(0)" ::: "memory");
    __syncthreads();

    unsigned target = tgt0;

    for (int s = 0; s < tcount; ++s) {
        const int v = lo + s;
        const int t = dir ? (255 - v) : v;
        const int ridx = (v + nbm) & nbm;   // buffer holding h_{v-1}
        const int widx = v & nbm;           // buffer to publish h_v

        float p0, p1, p2, p3;
        if (wid < 4) {
            const size_t col = (size_t)(scol0 + s*64) + bb;
            p0 = pre[((size_t)(dir*2048 +        kg))*ncols + col];
            p1 = pre[((size_t)(dir*2048 +  512 + kg))*ncols + col];
            p2 = pre[((size_t)(dir*2048 + 1024 + kg))*ncols + col];
            p3 = pre[((size_t)(dir*2048 + 1536 + kg))*ncols + col];
        }

        // ---- group barrier (32 blocks, single counter, relaxed) ----
        target += 32;
        if (tid == 0) {
            __hip_atomic_fetch_add(mycnt, 1u, __ATOMIC_RELAXED, __HIP_MEMORY_SCOPE_AGENT);
            while (__hip_atomic_load(mycnt, __ATOMIC_RELAXED, __HIP_MEMORY_SCOPE_AGENT) < target)
                __builtin_amdgcn_s_sleep(2);
        }
        __syncthreads();

        // ---- stage h_{v-1}[all k][b0..b0+16): PLAIN uint4 loads (L2-cached) ----
        const uint4* src4 = (const uint4*)(hbig + ((size_t)ridx*2 + dir)*32768);
#pragma unroll
        for (int i = 0; i < 4; ++i) {
            const int cc = i*512 + tid;
            const int bl = cc >> 7;
            const int jc = cc & 127;
            uint4 vv = src4[(size_t)(b0 + bl)*128 + jc];
            *(uint4*)(smem + LDS_B + jc*256 + ((bl ^ (jc & 7)) << 4)) = vv;
        }
        __syncthreads();

        // ---- mfma K-loop + epilogue (waves 0-3) ----
        if (wid < 4) {
            f32x4 acc = {p0, p1, p2, p3};
            const int arow = (wid*16 + dlt) << 10;
            const int axor = ((wid*16 + dlt) & 7) << 4;
            const int boff0 = (2*gma)*256   + ((dlt ^ (2*gma    )) << 4);
            const int boff1 = (2*gma+1)*256 + ((dlt ^ (2*gma + 1)) << 4);
#pragma unroll
            for (int kt = 0; kt < 16; ++kt) {
                const int jb  = (kt << 6) + (gma << 4);
                const int aof = arow + (jb ^ axor);
                short8 ah = *(const short8*)(smem + LDS_W_HI + aof);
                short8 al = *(const short8*)(smem + LDS_W_LO + aof);
                uint4 u0 = *(const uint4*)(smem + LDS_B + boff0 + (kt << 11));
                uint4 u1 = *(const uint4*)(smem + LDS_B + boff1 + (kt << 11));
                short8 bh, bl;
                unpack8(u0, u1, bh, bl);
                acc = __builtin_amdgcn_mfma_f32_16x16x32_bf16(ah, bh, acc, 0, 0, 0);
                acc = __builtin_amdgcn_mfma_f32_16x16x32_bf16(ah, bl, acc, 0, 0, 0);
                acc = __builtin_amdgcn_mfma_f32_16x16x32_bf16(al, bh, acc, 0, 0, 0);
            }
            float ig = fsig(acc[0]);
            float fg = fsig(acc[1]);
            float gg = ftanh(acc[2]);
            float og = fsig(acc[3]);
            c = fg * c + ig * gg;
            float h = og * ftanh(c);
            unsigned hpv = pack_split(h);
            // publish first, drain ONLY the publish, then issue out/cbuf stores
            astore_u32(hbig + ((size_t)widx*2 + dir)*32768 + (size_t)bb*512 + kg, hpv);
            asm volatile("s_waitcnt vmcnt(0)" ::: "memory");
            const size_t oidx = ((size_t)t*1024 + dir*512 + kg)*64 + bb;
            if (packout) ((unsigned*)outbuf)[oidx] = hpv;
            else         ((float*)outbuf)[oidx]    = h;
            if (s == tcount-1) cbuf[(size_t)dir*32768 + (size_t)kg*64 + bb] = c;
        }
        __syncthreads();   // all waves' publishes drained before tid0 re-arrives
    }
}

// ---------------- emissions (h1 f32) --------------------------------------------
__global__ __launch_bounds__(256) void emis_kernel(
    const float* __restrict__ h1, const float* __restrict__ Wout,
    const float* __restrict__ bout, float* __restrict__ em)
{
    const int s = blockIdx.x;
    const int tid = threadIdx.x;
    const int b = tid & 63;
    const int cl = tid >> 6;
    __shared__ float wl[32][128];
    float acc[8];
#pragma unroll
    for (int u = 0; u < 8; ++u) acc[u] = 0.f;
    const float* hp = h1 + (size_t)s * (1024*64);
    for (int f0 = 0; f0 < 1024; f0 += 128) {
        __syncthreads();
        for (int u = tid; u < 4096; u += 256) {
            int cc = u >> 7, ff = u & 127;
            wl[cc][ff] = Wout[(size_t)cc*1024 + f0 + ff];
        }
        __syncthreads();
        for (int ff = 0; ff < 128; ++ff) {
            float hv = hp[(size_t)(f0+ff)*64 + b];
#pragma unroll
            for (int u = 0; u < 8; ++u) acc[u] += hv * wl[cl + u*4][ff];
        }
    }
#pragma unroll
    for (int u = 0; u < 8; ++u) {
        int cc = cl + u*4;
        em[((size_t)b*T_ + s)*C_ + cc] = acc[u] + bout[cc];
    }
}

// ---------------- CRF Viterbi: r13 version (half-wave split max + em prefetch) --
__global__ __launch_bounds__(64) void viterbi_kernel(
    const float* __restrict__ em, const float* __restrict__ start_t,
    const float* __restrict__ end_t, const float* __restrict__ trans,
    float* __restrict__ dout)
{
    const int b = blockIdx.x;
    const int l = threadIdx.x;
    const int j = l & 31;
    const int half = l >> 5;
    __shared__ float tr[C_*C_];
    __shared__ float sc[2][C_];
    __shared__ unsigned char hist[T_-1][C_];
    const float* emb = em + (size_t)b * T_ * C_;
    for (int i = l; i < C_*C_; i += 64) tr[i] = trans[i];
    if (l < C_) sc[0][l] = start_t[l] + emb[l];
    __syncthreads();

    float em_next = emb[C_ + j];
    for (int s = 1; s < T_; ++s) {
        const int cur = (s-1) & 1, nxt = s & 1;
        float em_cur = em_next;
        if (s + 1 < T_) em_next = emb[(size_t)(s+1)*C_ + j];
        float best = -3.4e38f; int bi = 0;
#pragma unroll
        for (int q = 0; q < 16; ++q) {
            const int i = half*16 + q;
            float v = sc[cur][i] + tr[i*C_ + j];
            if (v > best) { best = v; bi = i; }
        }
        float obest = __shfl_xor(best, 32);
        int   obi   = __shfl_xor(bi, 32);
        if (half == 0) { if (obest >  best) { best = obest; bi = obi; } }
        else           { if (obest >= best) { best = obest; bi = obi; } }
        if (half == 0) {
            sc[nxt][j] = best + em_cur;
            hist[s-1][j] = (unsigned char)bi;
        }
        __syncthreads();
    }
    if (l == 0) {
        const int cur = (T_-1) & 1;
        float best = -3.4e38f; int bi = 0;
        for (int i = 0; i < C_; ++i) {
            float v = sc[cur][i] + end_t[i];
            if (v > best) { best = v; bi = i; }
        }
        dout[(size_t)B_*T_ + b] = best;
        float* tout = dout + (size_t)b * T_;
        int tag = bi;
        tout[T_-1] = (float)tag;
        for (int s = T_-2; s >= 0; --s) {
            tag = hist[s][tag];
            tout[s] = (float)tag;
        }
    }
}

// ---------------- host launch ---------------------------------------------------
extern "C" void kernel_launch(void* const* d_in, const int* in_sizes, int n_in,
                              void* d_out, int out_size, void* d_ws, size_t ws_size,
                              hipStream_t stream) {
    const float* x    = (const float*)d_in[0];
    const float* Wih0 = (const float*)d_in[2];
    const float* Whh0 = (const float*)d_in[3];
    const float* b0   = (const float*)d_in[4];
    const float* Wih1 = (const float*)d_in[5];
    const float* Whh1 = (const float*)d_in[6];
    const float* b1   = (const float*)d_in[7];
    const float* Wout = (const float*)d_in[8];
    const float* bout = (const float*)d_in[9];
    const float* st   = (const float*)d_in[10];
    const float* en   = (const float*)d_in[11];
    const float* tr   = (const float*)d_in[12];
    float* dout = (float*)d_out;

    char* ws = (char*)d_ws;
    const size_t o_bar  = 0;                                   // 4 KiB
    const size_t o_cbuf = 4096;                                // 256 KiB
    const size_t o_hbig = o_cbuf + 262144;                     // 16 MiB reserved
    const size_t o_h0   = o_hbig + 16777216;                   // 64 MiB (packed u32)
    const size_t o_h1   = o_h0 + (size_t)67108864;             // 64 MiB (f32)
    const size_t o_pre  = o_h1 + (size_t)67108864;             // GC MiB

    // tiers: GC = gemm chunk, SC = scan chunk (NBUF = SC rotating buffers, >=32)
    int GC, SC; bool packW;
    const size_t base = o_pre;
    if      (ws_size >= base + 67108864ULL + 20971520ULL) { GC = 64; SC = 64; packW = true;  }
    else if (ws_size >= base + 33554432ULL + 20971520ULL) { GC = 32; SC = 32; packW = true;  }
    else if (ws_size >= base + 33554432ULL)               { GC = 32; SC = 32; packW = false; }
    else                                                  { GC = 16; SC = 16; packW = false; }
    const int NBUFR = (SC < 32) ? 32 : SC;
    const int nbm = NBUFR - 1;
    const size_t presz = (size_t)4096 * GC * 64 * 4;
    const size_t o_w0pk = o_pre + presz;
    const size_t o_w1pk = o_w0pk + 4194304;
    const int ncols = GC * 64;

    unsigned* bar  = (unsigned*)(ws + o_bar);
    float* cbuf    = (float*)(ws + o_cbuf);
    unsigned* hbig = (unsigned*)(ws + o_hbig);
    unsigned* h0pk = (unsigned*)(ws + o_h0);
    float* h1      = (float*)(ws + o_h1);
    float* pre     = (float*)(ws + o_pre);
    float* em      = (float*)(ws + o_pre);    // aliases pre (pre dead by emis time)
    unsigned* w0pk = packW ? (unsigned*)(ws + o_w0pk) : nullptr;
    unsigned* w1pk = packW ? (unsigned*)(ws + o_w1pk) : nullptr;

    hipMemsetAsync(bar, 0, 4096, stream);

    const int LDS_BYTES = 163840;
    hipFuncSetAttribute(reinterpret_cast<const void*>(lstm_scan),
                        hipFuncAttributeMaxDynamicSharedMemorySize, LDS_BYTES);

    if (packW) {
        pack_kernel<<<1024, 256, 0, stream>>>(Wih0, w0pk, 4096*256);
        pack_kernel<<<2048, 256, 0, stream>>>(Wih1, w1pk, 4096*1024);
    }

    dim3 gg(ncols/128, 32), bb(256);
    for (int glo = 0; glo < 256; glo += GC) {
        gemm_mfma<<<gg, bb, 0, stream>>>(w0pk, Wih0, x, b0, pre, F0_, 0, glo, ncols);
        for (int slo = glo; slo < glo + GC; slo += SC)
            lstm_scan<<<256, 512, LDS_BYTES, stream>>>(
                Whh0, pre, h0pk, 1, hbig, cbuf, bar,
                slo, slo == 0 ? 1 : 0, (unsigned)(slo * 32), SC, ncols,
                (slo - glo) * 64, nbm);
    }
    for (int glo = 0; glo < 256; glo += GC) {
        gemm_mfma<<<gg, bb, 0, stream>>>(w1pk, Wih1, h0pk, b1, pre, 1024, 1, glo, ncols);
        for (int slo = glo; slo < glo + GC; slo += SC)
            lstm_scan<<<256, 512, LDS_BYTES, stream>>>(
                Whh1, pre, h1, 0, hbig, cbuf, bar,
                slo, slo == 0 ? 1 : 0, (unsigned)((256 + slo) * 32), SC, ncols,
                (slo - glo) * 64, nbm);
    }
    emis_kernel<<<T_, bb, 0, stream>>>(h1, Wout, bout, em);
    viterbi_kernel<<<B_, 64, 0, stream>>>(em, st, en, tr, dout);
}